// Round 10
// baseline (198.311 us; speedup 1.0000x reference)
//
#include <hip/hip_runtime.h>

// ---------------------------------------------------------------------------
// SelfAttention (B=4,T=2048,D=1024,H=16,hd=64) fp32 in/out, bf16 MFMA compute.
// Pipeline (4 kernels): prep -> gemm_qkv9 (256x256, BK=64, 4-phase/K-tile
// counted-vmcnt pipeline, writes Q/K frag16x64 + V^T frag16x64) -> flash7 ->
// out gemm (verified 128x128 structure).
//
// frag16x64 layout: matrix [R][64] stored per 16-row block:
//   addr(row,col) = (row>>4)*1024 + (col>>5)*512 + ((col>>3)&3)*128
//                 + (row&15)*8 + (col&7)
// ---------------------------------------------------------------------------

typedef __bf16 bf16_t;
typedef bf16_t bf16x8 __attribute__((ext_vector_type(8)));
typedef float  f32x4  __attribute__((ext_vector_type(4)));
typedef unsigned u32x4 __attribute__((ext_vector_type(4)));
typedef unsigned short u16x8 __attribute__((ext_vector_type(8)));
typedef unsigned short u16x4 __attribute__((ext_vector_type(4)));

#define DEV static __device__ __forceinline__

constexpr int Bc = 4, Tc = 2048, Dc = 1024, Hc = 16, HDc = 64;
constexpr int Mc = Bc * Tc;        // 8192 rows
constexpr int NQKV = 3 * Dc;       // 3072

DEV unsigned short f2bf(float f) {
  union { float f; unsigned u; } v; v.f = f;
  return (unsigned short)((v.u + 0x7fffu + ((v.u >> 16) & 1u)) >> 16);
}

DEV void gload_lds16(const void* g, const void* ldsbase) {
  unsigned m0v = __builtin_amdgcn_readfirstlane((unsigned)(unsigned long long)ldsbase);
  asm volatile("s_mov_b32 m0, %0\n\t"
               "global_load_lds_dwordx4 %1, off"
               :: "s"(m0v), "v"(g) : "memory");
}

DEV f32x4 mfma16(bf16x8 a, bf16x8 b, f32x4 c) {
  return __builtin_amdgcn_mfma_f32_16x16x32_bf16(a, b, c, 0, 0, 0);
}

DEV void pl32swap(unsigned& a, unsigned& b) {
  asm("v_permlane32_swap_b32 %0, %1" : "+v"(a), "+v"(b));
}
DEV void pl16swap(unsigned& a, unsigned& b) {
  asm("v_permlane16_swap_b32 %0, %1" : "+v"(a), "+v"(b));
}

// frag16x64 element address (row within a [R][64] matrix)
DEV int fragaddr(int row, int col) {
  return (row >> 4) * 1024 + ((col >> 5) << 9) + (((col >> 3) & 3) << 7)
       + ((row & 15) << 3) + (col & 7);
}

// ---------------------------------------------------------------------------
// prep: fused cvt_embed (blocks 0..8191) + wt_cvt (8192..9215) + bias (9216)
// ---------------------------------------------------------------------------
__global__ __launch_bounds__(256) void prep(const float* __restrict__ embed,
                                            const float* __restrict__ Wq,
                                            const float* __restrict__ Wk,
                                            const float* __restrict__ Wv,
                                            const float* __restrict__ Wo,
                                            const float* __restrict__ bq,
                                            const float* __restrict__ bk,
                                            const float* __restrict__ bv,
                                            unsigned short* __restrict__ embed_bf,
                                            unsigned short* __restrict__ WtAll,
                                            float* __restrict__ ball) {
  __shared__ unsigned short tile[64 * 80];
  const int bb = blockIdx.x;
  const int tid = threadIdx.x;

  if (bb < 8192) {                                   // ---- embed f32 -> bf16
    int i = bb * 256 + tid;
    float4 v = ((const float4*)embed)[i];
    u16x4 o = { f2bf(v.x), f2bf(v.y), f2bf(v.z), f2bf(v.w) };
    *(u16x4*)(embed_bf + (size_t)i * 4) = o;
    return;
  }
  if (bb < 8192 + 1024) {                            // ---- W -> W^T bf16
    int wb = bb - 8192;
    int bx = wb & 15, by = (wb >> 4) & 15, bz = wb >> 8;
    const float* W = bz == 0 ? Wq : bz == 1 ? Wk : bz == 2 ? Wv : Wo;
    unsigned short* dst = WtAll + (size_t)bz * 1024 * 1024;
    const int kb = by * 64, nb = bx * 64;
#pragma unroll
    for (int i = 0; i < 4; i++) {
      int ci = i * 256 + tid;
      int r = ci >> 4, c4 = ci & 15;
      float4 v = *(const float4*)(W + (size_t)(kb + r) * 1024 + nb + c4 * 4);
      u16x4 o = { f2bf(v.x), f2bf(v.y), f2bf(v.z), f2bf(v.w) };
      *(u16x4*)(tile + r * 80 + c4 * 4) = o;
    }
    __syncthreads();
#pragma unroll
    for (int i = 0; i < 2; i++) {
      int ci = i * 256 + tid;
      int n = ci >> 3, c8 = ci & 7;
      u16x8 o;
#pragma unroll
      for (int j = 0; j < 8; j++) o[j] = tile[(c8 * 8 + j) * 80 + n];
      *(u16x8*)(dst + (size_t)(nb + n) * 1024 + kb + c8 * 8) = o;
    }
    return;
  }
  // ---- bias concat (single block)
#pragma unroll
  for (int it = 0; it < 12; it++) {
    int i = it * 256 + tid;
    ball[i] = (i < 1024) ? bq[i] : (i < 2048) ? bk[i - 1024] : bv[i - 2048];
  }
}

// ---------------------------------------------------------------------------
// gemm_qkv9: QKV projection. BM=BN=256, BK=64, 512 thr = 8 waves (2M x 4N),
// wave-tile 128x64, acc[8][4]. LDS = 2dbuf x 2half x 128x64 x {A,B} = 128KB.
// 4 phases per K-tile (one C-quadrant x K=64 each, 16 MFMA). Phase:
//   {ds_read subtile; lgkmcnt(0); barrier; stage 1 half-tile (2 gload_lds);
//    setprio(1); 16 MFMA; setprio(0); [vmcnt(4) at q3]; barrier}
// Staging 6 phases ahead (half-tile s staged at global phase s-6); vmcnt(4)
// once per K-tile keeps 2 half-tiles (4 loads) in flight. WAR: each slot's
// stage is behind a barrier that follows the slot's last reads. RAW: vmcnt(4)
// at kt's q3 confirms next K-tile's 4 half-tiles landed.
// Half-tile s: K-tile ts=s>>2 (dbuf ts&1), j=s&3: 0/1 -> A half j, 2/3 -> B
// half j-2. A halves split wave rows (wr), B halves split wave cols (wc>>1).
// Swizzle: 8 chunks/row, phys = chunk ^ (row&7)  (verified 2-way-free).
// Epilogue: Q (scaled 0.125*log2e)/K -> frag16x64; V -> V^T frag16x64.
// ---------------------------------------------------------------------------
__global__ __launch_bounds__(512, 2) void gemm_qkv9(
    const unsigned short* __restrict__ A,      // embed_bf [8192][1024]
    const unsigned short* __restrict__ Bt,     // WtAll    [3072][1024]
    const float* __restrict__ bias,            // ball[3072]
    unsigned short* __restrict__ Qf,
    unsigned short* __restrict__ Kf,
    unsigned short* __restrict__ Vf) {
  __shared__ unsigned short LA[32768];         // [d][h][128][64] 64 KB
  __shared__ unsigned short LB[32768];         // 64 KB

  const int tid = threadIdx.x;
  const int lane = tid & 63, wid = tid >> 6;
  const int lr = lane & 15, lg = lane >> 4;
  const int wr = wid >> 2, wc = wid & 3;

  // grid (12 N, 32 M); XCD-bijective swizzle
  const int lin = blockIdx.y * 12 + blockIdx.x;        // 0..383
  const int swz = (lin & 7) * 48 + (lin >> 3);
  const int m0 = (swz / 12) * 256, n0 = (swz % 12) * 256;

  // staging per-thread constants: half-tile = 128 rows x 8 chunks of 16B
  int srow[2], scl[2], sdst[2];
#pragma unroll
  for (int i = 0; i < 2; i++) {
    int ci = i * 512 + tid;
    srow[i] = ci >> 3;
    scl[i] = (ci & 7) ^ (srow[i] & 7);
    sdst[i] = ci * 8;
  }

#define STG(s_) {                                                            \
    const int ts_ = (s_) >> 2, j_ = (s_) & 3, d_ = ts_ & 1;                  \
    _Pragma("unroll")                                                        \
    for (int i_ = 0; i_ < 2; i_++) {                                         \
      if (j_ < 2)                                                            \
        gload_lds16(A + (size_t)(m0 + j_ * 128 + srow[i_]) * 1024            \
                      + ts_ * 64 + scl[i_] * 8,                              \
                    LA + (d_ * 2 + j_) * 8192 + sdst[i_]);                   \
      else                                                                   \
        gload_lds16(Bt + (size_t)(n0 + (j_ - 2) * 128 + srow[i_]) * 1024     \
                       + ts_ * 64 + scl[i_] * 8,                             \
                    LB + (d_ * 2 + (j_ - 2)) * 8192 + sdst[i_]);             \
    } }

  // read-offset constants
  const int aoff = lr * 64;
  const int co0 = (lg ^ (lr & 7)) << 3;            // kk=0 chunk slot
  const int co1 = ((4 + lg) ^ (lr & 7)) << 3;      // kk=1
  const int bhalf = (wc & 1) * 4096;

  f32x4 acc[8][4] = {};
  bf16x8 aR[4][2], bR[4][2];

#define RD_A(Ad_, mbase_) {                                                  \
    _Pragma("unroll")                                                        \
    for (int m_ = 0; m_ < 4; m_++) {                                         \
      aR[m_][0] = *(const bf16x8*)((Ad_) + ((mbase_) + m_) * 1024 + aoff + co0); \
      aR[m_][1] = *(const bf16x8*)((Ad_) + ((mbase_) + m_) * 1024 + aoff + co1); \
    } }
#define RD_B(Bd_, nlo_) {                                                    \
    _Pragma("unroll")                                                        \
    for (int n_ = 0; n_ < 2; n_++) {                                         \
      bR[(nlo_) + n_][0] = *(const bf16x8*)((Bd_) + bhalf + ((nlo_) + n_) * 1024 + aoff + co0); \
      bR[(nlo_) + n_][1] = *(const bf16x8*)((Bd_) + bhalf + ((nlo_) + n_) * 1024 + aoff + co1); \
    } }
#define MFMA16(mb_, nl_) {                                                   \
    __builtin_amdgcn_s_setprio(1);                                           \
    _Pragma("unroll")                                                        \
    for (int m_ = 0; m_ < 4; m_++)                                           \
      _Pragma("unroll")                                                      \
      for (int n_ = 0; n_ < 2; n_++) {                                       \
        acc[(mb_) + m_][(nl_) + n_] =                                        \
            mfma16(aR[m_][0], bR[(nl_) + n_][0], acc[(mb_) + m_][(nl_) + n_]); \
        acc[(mb_) + m_][(nl_) + n_] =                                        \
            mfma16(aR[m_][1], bR[(nl_) + n_][1], acc[(mb_) + m_][(nl_) + n_]); \
      }                                                                      \
    __builtin_amdgcn_s_setprio(0); }

#define LGKM0 { asm volatile("s_waitcnt lgkmcnt(0)" ::: "memory");           \
                __builtin_amdgcn_sched_barrier(0); }
#define BAR   { asm volatile("s_barrier" ::: "memory"); }

// one K-tile = 4 phases. DO2/DO3: whether q2/q3 stage (false only at kt>=14).
// VMq3: vmcnt string at q3 ("4" steady, "0" at kt=14 drain, skip at kt=15).
#define KTILE(kt_, DO01, DO2, DO3, DOVM, VMq3) {                             \
    const unsigned short* Ad = LA + wr * 8192 + ((kt_) & 1) * 16384;         \
    const unsigned short* Bd = LB + (wc >> 1) * 8192 + ((kt_) & 1) * 16384;  \
    /* q0 */                                                                 \
    RD_A(Ad, 0); RD_B(Bd, 0);                                                \
    LGKM0; BAR;                                                              \
    if (DO01) STG(4 * (kt_) + 6);                                            \
    MFMA16(0, 0); BAR;                                                       \
    /* q1 */                                                                 \
    RD_B(Bd, 2);                                                             \
    LGKM0; BAR;                                                              \
    if (DO01) STG(4 * (kt_) + 7);                                            \
    MFMA16(0, 2); BAR;                                                       \
    /* q2 */                                                                 \
    RD_A(Ad, 4);                                                             \
    LGKM0; BAR;                                                              \
    if (DO2) STG(4 * (kt_) + 8);                                             \
    MFMA16(4, 0); BAR;                                                       \
    /* q3 */                                                                 \
    if (DO3) STG(4 * (kt_) + 9);                                             \
    MFMA16(4, 2);                                                            \
    if (DOVM) { asm volatile("s_waitcnt vmcnt(" VMq3 ")" ::: "memory"); }    \
    BAR; }

  // prologue: half-tiles 0..5 (K-tiles 0,1 A+B; K-tile 1's A) in flight
  STG(0); STG(1); STG(2); STG(3); STG(4); STG(5);
  asm volatile("s_waitcnt vmcnt(4)" ::: "memory");
  BAR;

#pragma unroll 1
  for (int kt = 0; kt < 14; ++kt) {
    KTILE(kt, 1, 1, 1, 1, "4");
  }
  KTILE(14, 1, 0, 0, 1, "0");
  KTILE(15, 0, 0, 0, 0, "0");

#undef KTILE
#undef BAR
#undef LGKM0
#undef MFMA16
#undef RD_B
#undef RD_A
#undef STG

  // epilogue: scatter into Q/K frag16x64, V -> V^T frag16x64
#pragma unroll
  for (int m = 0; m < 8; m++)
#pragma unroll
    for (int n = 0; n < 4; n++)
#pragma unroll
      for (int r = 0; r < 4; r++) {
        int row = m0 + wr * 128 + m * 16 + lg * 4 + r;
        int col = n0 + wc * 64 + n * 16 + lr;
        float v = acc[m][n][r] + bias[col];
        int bb = row >> 11, tl = row & 2047;
        if (col < Dc) {                                  // Q, scaled
          v *= 0.18033688f;                              // (1/8)*log2(e)
          int h = col >> 6, d = col & 63;
          Qf[(size_t)(bb * 16 + h) * 131072 + fragaddr(tl, d)] = f2bf(v);
        } else if (col < 2 * Dc) {                       // K
          int c = col - Dc, h = c >> 6, d = c & 63;
          Kf[(size_t)(bb * 16 + h) * 131072 + fragaddr(tl, d)] = f2bf(v);
        } else {                                         // V -> V^T frag
          int c = col - 2 * Dc, h = c >> 6, d = c & 63;
          Vf[(size_t)(bb * 16 + h) * 131072 + (tl >> 6) * 4096 + fragaddr(d, tl & 63)] = f2bf(v);
        }
      }
}

// ---------------------------------------------------------------------------
// gemm_bt (verified 128x128 structure) -- output projection, fp32 out.
// ---------------------------------------------------------------------------
__global__ __launch_bounds__(256) void gemm_bt(const unsigned short* __restrict__ A,
                                               const unsigned short* __restrict__ Bt,
                                               const float* __restrict__ bias,
                                               float* __restrict__ Cout,
                                               int N, int K) {
  __shared__ unsigned short As[128 * 64];
  __shared__ unsigned short Bs[128 * 64];
  const int tid = threadIdx.x;
  const int lane = tid & 63, wid = tid >> 6;
  const int lr = lane & 15, lg = lane >> 4;
  const int wrow = wid >> 1, wcol = wid & 1;
  const int m0 = blockIdx.y * 128, n0 = blockIdx.x * 128;

  f32x4 acc[4][4] = {};

  for (int k0 = 0; k0 < K; k0 += 64) {
#pragma unroll
    for (int i = 0; i < 4; i++) {
      int ci = i * 256 + tid;
      int row = ci >> 3, ph = ci & 7;
      int cl = ph ^ (row & 7);
      gload_lds16(A + (size_t)(m0 + row) * K + k0 + cl * 8, As + (size_t)(i * 256 + wid * 64) * 8);
      gload_lds16(Bt + (size_t)(n0 + row) * K + k0 + cl * 8, Bs + (size_t)(i * 256 + wid * 64) * 8);
    }
    asm volatile("s_waitcnt vmcnt(0)" ::: "memory");
    __syncthreads();
#pragma unroll
    for (int kk = 0; kk < 2; kk++) {
      bf16x8 av[4], bv[4];
#pragma unroll
      for (int m = 0; m < 4; m++) {
        int row = wrow * 64 + m * 16 + lr;
        int ph = (kk * 4 + lg) ^ (row & 7);
        av[m] = *(const bf16x8*)(As + row * 64 + ph * 8);
      }
#pragma unroll
      for (int n = 0; n < 4; n++) {
        int row = wcol * 64 + n * 16 + lr;
        int ph = (kk * 4 + lg) ^ (row & 7);
        bv[n] = *(const bf16x8*)(Bs + row * 64 + ph * 8);
      }
#pragma unroll
      for (int m = 0; m < 4; m++)
#pragma unroll
        for (int n = 0; n < 4; n++)
          acc[m][n] = mfma16(av[m], bv[n], acc[m][n]);
    }
    __syncthreads();
  }

#pragma unroll
  for (int m = 0; m < 4; m++)
#pragma unroll
    for (int n = 0; n < 4; n++)
#pragma unroll
      for (int r = 0; r < 4; r++) {
        int row = m0 + wrow * 64 + m * 16 + lg * 4 + r;
        int col = n0 + wcol * 64 + n * 16 + lr;
        Cout[(size_t)row * N + col] = acc[m][n][r] + bias[col];
      }
}

// ---------------------------------------------------------------------------
// flash7 (byte-identical to verified round-9 kernel)
// ---------------------------------------------------------------------------
__global__ __launch_bounds__(256, 2) void flash7(const unsigned short* __restrict__ Qf,
                                                 const unsigned short* __restrict__ Kf,
                                                 const unsigned short* __restrict__ Vf,
                                                 const int* __restrict__ mask,
                                                 unsigned short* __restrict__ merged) {
  const int tid = threadIdx.x;
  const int lane = tid & 63, wid = tid >> 6;
  const int lr = lane & 15, lg = lane >> 4;

  // XCD-bijective swizzle: 8 q-blocks of one head land on one XCD.
  const int lin = blockIdx.y * 8 + blockIdx.x;      // 0..511
  const int swz = (lin & 7) * 64 + (lin >> 3);
  const int qb = swz & 7, bh = swz >> 3;
  const int b = bh >> 4, h = bh & 15;
  const int wq = qb * 256 + wid * 64;               // wave's q base

  const unsigned short* Qb = Qf + (size_t)bh * 131072;
  const unsigned short* Kb = Kf + (size_t)bh * 131072;
  const unsigned short* Vb = Vf + (size_t)bh * 131072;

  bf16x8 qf[4][2];
#pragma unroll
  for (int qn = 0; qn < 4; qn++)
#pragma unroll
    for (int kk = 0; kk < 2; kk++)
      qf[qn][kk] = *(const bf16x8*)(Qb + ((wq >> 4) + qn) * 1024 + kk * 512 + lane * 8);

  f32x4 o[4][4] = {};
  f32x4 lacc[4] = {};

  bf16x8 ones;
#pragma unroll
  for (int j = 0; j < 8; j++) ones[j] = (bf16_t)1.0f;

  // whole-mask all-ones check (8 coalesced int4 loads), hoisted
  bool allone = true;
#pragma unroll
  for (int j = 0; j < 8; j++) {
    int4 mv = ((const int4*)mask)[j * 64 + lane];
    allone = allone && (mv.x != 0) && (mv.y != 0) && (mv.z != 0) && (mv.w != 0);
  }
  const bool nomask = (__ballot(allone) == ~0ull);

#pragma unroll 2
  for (int tile = 0; tile < 32; tile++) {
    bf16x8 kf[4][2];
#pragma unroll
    for (int n = 0; n < 4; n++)
#pragma unroll
      for (int kk = 0; kk < 2; kk++)
        kf[n][kk] = *(const bf16x8*)(Kb + (tile * 4 + n) * 1024 + kk * 512 + lane * 8);
    bf16x8 vf[4][2];
#pragma unroll
    for (int dn = 0; dn < 4; dn++)
#pragma unroll
      for (int kk = 0; kk < 2; kk++)
        vf[dn][kk] = *(const bf16x8*)(Vb + tile * 4096 + dn * 1024 + kk * 512 + lane * 8);

    unsigned long long mb = ~0ull;
    if (!nomask) mb = __ballot(mask[tile * 64 + lane] != 0);

    unsigned pk[4][4][2];
#pragma unroll
    for (int kvn = 0; kvn < 4; kvn++) {
      f32x4 st[4] = {};
#pragma unroll
      for (int qn = 0; qn < 4; qn++) {
        st[qn] = mfma16(kf[kvn][0], qf[qn][0], st[qn]);
        st[qn] = mfma16(kf[kvn][1], qf[qn][1], st[qn]);
      }
      if (mb != ~0ull) {
#pragma unroll
        for (int r = 0; r < 4; r++)
          if (!((mb >> (kvn * 16 + lg * 4 + r)) & 1ull)) {
#pragma unroll
            for (int qn = 0; qn < 4; qn++) st[qn][r] = -1e30f;
          }
      }
#pragma unroll
      for (int qn = 0; qn < 4; qn++) {
        float e[4];
#pragma unroll
        for (int r = 0; r < 4; r++)
          asm("v_exp_f32 %0, %1" : "=v"(e[r]) : "v"(st[qn][r]));
        asm("v_cvt_pk_bf16_f32 %0, %1, %2" : "=v"(pk[qn][kvn][0]) : "v"(e[0]), "v"(e[1]));
        asm("v_cvt_pk_bf16_f32 %0, %1, %2" : "=v"(pk[qn][kvn][1]) : "v"(e[2]), "v"(e[3]));
      }
    }

    bf16x8 pa[4][2];
#pragma unroll
    for (int qn = 0; qn < 4; qn++)
#pragma unroll
      for (int m = 0; m < 2; m++) {
        unsigned a0 = pk[qn][2 * m][0], b0 = pk[qn][2 * m + 1][0];
        unsigned a1 = pk[qn][2 * m][1], b1 = pk[qn][2 * m + 1][1];
        pl32swap(a0, b0);
        pl32swap(a1, b1);
        pl16swap(a0, b0);
        pl16swap(a1, b1);
        u32x4 w = { a0, a1, b0, b1 };
        pa[qn][m] = __builtin_bit_cast(bf16x8, w);
      }

    __builtin_amdgcn_s_setprio(1);
#pragma unroll
    for (int qn = 0; qn < 4; qn++) {
#pragma unroll
      for (int dn = 0; dn < 4; dn++) {
        o[qn][dn] = mfma16(pa[qn][0], vf[dn][0], o[qn][dn]);
        o[qn][dn] = mfma16(pa[qn][1], vf[dn][1], o[qn][dn]);
      }
      lacc[qn] = mfma16(pa[qn][0], ones, lacc[qn]);
      lacc[qn] = mfma16(pa[qn][1], ones, lacc[qn]);
    }
    __builtin_amdgcn_s_setprio(0);
  }

#pragma unroll
  for (int qn = 0; qn < 4; qn++)
#pragma unroll
    for (int r = 0; r < 4; r++) {
      float inv = 1.0f / lacc[qn][r];
      int grow = b * Tc + wq + qn * 16 + lg * 4 + r;
#pragma unroll
      for (int dn = 0; dn < 4; dn++) {
        int gcol = h * HDc + dn * 16 + lr;
        merged[(size_t)grow * Dc + gcol] = f2bf(o[qn][dn][r] * inv);
      }
    }
}

// ---------------------------------------------------------------------------
extern "C" void kernel_launch(void* const* d_in, const int* in_sizes, int n_in,
                              void* d_out, int out_size, void* d_ws, size_t ws_size,
                              hipStream_t stream) {
  const float* embed = (const float*)d_in[0];
  const int*   mask  = (const int*)d_in[1];
  const float* Wq = (const float*)d_in[2];
  const float* bq = (const float*)d_in[3];
  const float* Wk = (const float*)d_in[4];
  const float* bk = (const float*)d_in[5];
  const float* Wv = (const float*)d_in[6];
  const float* bv = (const float*)d_in[7];
  const float* Wo = (const float*)d_in[8];
  const float* bo = (const float*)d_in[9];
  float* out = (float*)d_out;

  char* ws = (char*)d_ws;
  unsigned short* embed_bf = (unsigned short*)ws; ws += (size_t)Mc * Dc * 2;        // 16.8 MB
  unsigned short* WtAll    = (unsigned short*)ws; ws += (size_t)4 * Dc * Dc * 2;    //  8.4 MB
  float*          ball     = (float*)ws;          ws += 16384;
  unsigned short* Qf       = (unsigned short*)ws; ws += (size_t)Mc * Dc * 2;        // 16.8 MB
  unsigned short* Kf       = (unsigned short*)ws; ws += (size_t)Mc * Dc * 2;        // 16.8 MB
  unsigned short* Vf       = (unsigned short*)ws; ws += (size_t)Mc * Dc * 2;        // 16.8 MB
  unsigned short* merged   = (unsigned short*)ws; ws += (size_t)Mc * Dc * 2;        // 16.8 MB

  prep<<<8192 + 1024 + 1, 256, 0, stream>>>(embed, Wq, Wk, Wv, Wo, bq, bk, bv,
                                            embed_bf, WtAll, ball);
  gemm_qkv9<<<dim3(12, 32), 512, 0, stream>>>(embed_bf, WtAll, ball, Qf, Kf, Vf);
  flash7<<<dim3(8, 64), 256, 0, stream>>>(Qf, Kf, Vf, mask, merged);
  gemm_bt<<<dim3(8, 64), 256, 0, stream>>>(merged, WtAll + (size_t)3 * Dc * Dc, bo, out, Dc, Dc);
}

// Round 11
// 195.190 us; speedup vs baseline: 1.0160x; 1.0160x over previous
//
#include <hip/hip_runtime.h>

// ---------------------------------------------------------------------------
// SelfAttention (B=4,T=2048,D=1024,H=16,hd=64) fp32 in/out, bf16 MFMA compute.
// Pipeline (4 kernels): prep -> gemm_qkv10 (256x256, BK=64, m201-ordered
// 4-phase counted-vmcnt pipeline) -> flash7 -> out gemm (128x128 verified).
//
// frag16x64 layout: matrix [R][64] stored per 16-row block:
//   addr(row,col) = (row>>4)*1024 + (col>>5)*512 + ((col>>3)&3)*128
//                 + (row&15)*8 + (col&7)
// ---------------------------------------------------------------------------

typedef __bf16 bf16_t;
typedef bf16_t bf16x8 __attribute__((ext_vector_type(8)));
typedef float  f32x4  __attribute__((ext_vector_type(4)));
typedef unsigned u32x4 __attribute__((ext_vector_type(4)));
typedef unsigned short u16x8 __attribute__((ext_vector_type(8)));
typedef unsigned short u16x4 __attribute__((ext_vector_type(4)));

#define DEV static __device__ __forceinline__

constexpr int Bc = 4, Tc = 2048, Dc = 1024, Hc = 16, HDc = 64;
constexpr int Mc = Bc * Tc;        // 8192 rows
constexpr int NQKV = 3 * Dc;       // 3072

DEV unsigned short f2bf(float f) {
  union { float f; unsigned u; } v; v.f = f;
  return (unsigned short)((v.u + 0x7fffu + ((v.u >> 16) & 1u)) >> 16);
}

DEV void gload_lds16(const void* g, const void* ldsbase) {
  unsigned m0v = __builtin_amdgcn_readfirstlane((unsigned)(unsigned long long)ldsbase);
  asm volatile("s_mov_b32 m0, %0\n\t"
               "global_load_lds_dwordx4 %1, off"
               :: "s"(m0v), "v"(g) : "memory");
}

DEV f32x4 mfma16(bf16x8 a, bf16x8 b, f32x4 c) {
  return __builtin_amdgcn_mfma_f32_16x16x32_bf16(a, b, c, 0, 0, 0);
}

DEV void pl32swap(unsigned& a, unsigned& b) {
  asm("v_permlane32_swap_b32 %0, %1" : "+v"(a), "+v"(b));
}
DEV void pl16swap(unsigned& a, unsigned& b) {
  asm("v_permlane16_swap_b32 %0, %1" : "+v"(a), "+v"(b));
}

// frag16x64 element address (row within a [R][64] matrix)
DEV int fragaddr(int row, int col) {
  return (row >> 4) * 1024 + ((col >> 5) << 9) + (((col >> 3) & 3) << 7)
       + ((row & 15) << 3) + (col & 7);
}

// ---------------------------------------------------------------------------
// prep: fused cvt_embed (blocks 0..8191) + wt_cvt (8192..9215) + bias (9216)
// ---------------------------------------------------------------------------
__global__ __launch_bounds__(256) void prep(const float* __restrict__ embed,
                                            const float* __restrict__ Wq,
                                            const float* __restrict__ Wk,
                                            const float* __restrict__ Wv,
                                            const float* __restrict__ Wo,
                                            const float* __restrict__ bq,
                                            const float* __restrict__ bk,
                                            const float* __restrict__ bv,
                                            unsigned short* __restrict__ embed_bf,
                                            unsigned short* __restrict__ WtAll,
                                            float* __restrict__ ball) {
  __shared__ unsigned short tile[64 * 80];
  const int bb = blockIdx.x;
  const int tid = threadIdx.x;

  if (bb < 8192) {                                   // ---- embed f32 -> bf16
    int i = bb * 256 + tid;
    float4 v = ((const float4*)embed)[i];
    u16x4 o = { f2bf(v.x), f2bf(v.y), f2bf(v.z), f2bf(v.w) };
    *(u16x4*)(embed_bf + (size_t)i * 4) = o;
    return;
  }
  if (bb < 8192 + 1024) {                            // ---- W -> W^T bf16
    int wb = bb - 8192;
    int bx = wb & 15, by = (wb >> 4) & 15, bz = wb >> 8;
    const float* W = bz == 0 ? Wq : bz == 1 ? Wk : bz == 2 ? Wv : Wo;
    unsigned short* dst = WtAll + (size_t)bz * 1024 * 1024;
    const int kb = by * 64, nb = bx * 64;
#pragma unroll
    for (int i = 0; i < 4; i++) {
      int ci = i * 256 + tid;
      int r = ci >> 4, c4 = ci & 15;
      float4 v = *(const float4*)(W + (size_t)(kb + r) * 1024 + nb + c4 * 4);
      u16x4 o = { f2bf(v.x), f2bf(v.y), f2bf(v.z), f2bf(v.w) };
      *(u16x4*)(tile + r * 80 + c4 * 4) = o;
    }
    __syncthreads();
#pragma unroll
    for (int i = 0; i < 2; i++) {
      int ci = i * 256 + tid;
      int n = ci >> 3, c8 = ci & 7;
      u16x8 o;
#pragma unroll
      for (int j = 0; j < 8; j++) o[j] = tile[(c8 * 8 + j) * 80 + n];
      *(u16x8*)(dst + (size_t)(nb + n) * 1024 + kb + c8 * 8) = o;
    }
    return;
  }
  // ---- bias concat (single block)
#pragma unroll
  for (int it = 0; it < 12; it++) {
    int i = it * 256 + tid;
    ball[i] = (i < 1024) ? bq[i] : (i < 2048) ? bk[i - 1024] : bv[i - 2048];
  }
}

// ---------------------------------------------------------------------------
// gemm_qkv10: QKV projection. BM=BN=256, BK=64, 512 thr = 8 waves (2M x 4N),
// wave-tile 128x64, acc[8][4]. LDS = 2dbuf x 2half x 128x64 x {A,B} = 128KB.
// m201 phase order: {RD issue; STG issue; s_barrier; lgkmcnt(0); 16 MFMA;
// s_barrier}. Stages: q0 -> B0(kt+1), q1 -> B1(kt+1) (target dbuf != current,
// safe vs all in-flight reads), q3 -> A0+A1(kt+2) (targets last read at q2,
// whose readers passed q2's trailing barrier). vmcnt(4) once per K-tile at q3
// (A(kt+2)'s 4 loads in flight; confirms A(kt+1)+B(kt+1) landed), before the
// phase barrier so the guarantee is collective. Tail: kt=14 vmcnt(0), kt=15
// no stages. Swizzle: 8 chunks/row, phys = chunk ^ (row&7).
// Epilogue: Q (scaled 0.125*log2e)/K -> frag16x64; V -> V^T frag16x64.
// ---------------------------------------------------------------------------
__global__ __launch_bounds__(512, 2) void gemm_qkv10(
    const unsigned short* __restrict__ A,      // embed_bf [8192][1024]
    const unsigned short* __restrict__ Bt,     // WtAll    [3072][1024]
    const float* __restrict__ bias,            // ball[3072]
    unsigned short* __restrict__ Qf,
    unsigned short* __restrict__ Kf,
    unsigned short* __restrict__ Vf) {
  __shared__ unsigned short LA[32768];         // [dbuf][half][128][64] 64 KB
  __shared__ unsigned short LB[32768];         // 64 KB

  const int tid = threadIdx.x;
  const int lane = tid & 63, wid = tid >> 6;
  const int lr = lane & 15, lg = lane >> 4;
  const int wr = wid >> 2, wc = wid & 3;

  // grid (12 N, 32 M); XCD-bijective swizzle
  const int lin = blockIdx.y * 12 + blockIdx.x;        // 0..383
  const int swz = (lin & 7) * 48 + (lin >> 3);
  const int m0 = (swz / 12) * 256, n0 = (swz % 12) * 256;

  // staging per-thread constants: half-tile = 128 rows x 8 chunks of 16B
  int srow[2], scl[2], sdst[2];
#pragma unroll
  for (int i = 0; i < 2; i++) {
    int ci = i * 512 + tid;
    srow[i] = ci >> 3;
    scl[i] = (ci & 7) ^ (srow[i] & 7);
    sdst[i] = ci * 8;
  }

#define STGA(ts_, j_) {                                                      \
    _Pragma("unroll")                                                        \
    for (int i_ = 0; i_ < 2; i_++)                                           \
      gload_lds16(A + (size_t)(m0 + (j_) * 128 + srow[i_]) * 1024            \
                    + (ts_) * 64 + scl[i_] * 8,                              \
                  LA + ((((ts_) & 1) * 2 + (j_)) * 8192) + sdst[i_]); }
#define STGB(ts_, j_) {                                                      \
    _Pragma("unroll")                                                        \
    for (int i_ = 0; i_ < 2; i_++)                                           \
      gload_lds16(Bt + (size_t)(n0 + (j_) * 128 + srow[i_]) * 1024           \
                     + (ts_) * 64 + scl[i_] * 8,                             \
                  LB + ((((ts_) & 1) * 2 + (j_)) * 8192) + sdst[i_]); }

  // read-offset constants
  const int aoff = lr * 64;
  const int co0 = (lg ^ (lr & 7)) << 3;            // kk=0 chunk slot
  const int co1 = ((4 + lg) ^ (lr & 7)) << 3;      // kk=1
  const int bhalf = (wc & 1) * 4096;

  f32x4 acc[8][4] = {};
  bf16x8 aR[4][2], bR[4][2];

#define RD_A(Ad_, mbase_) {                                                  \
    _Pragma("unroll")                                                        \
    for (int m_ = 0; m_ < 4; m_++) {                                         \
      aR[m_][0] = *(const bf16x8*)((Ad_) + ((mbase_) + m_) * 1024 + aoff + co0); \
      aR[m_][1] = *(const bf16x8*)((Ad_) + ((mbase_) + m_) * 1024 + aoff + co1); \
    } }
#define RD_B(Bd_, nlo_) {                                                    \
    _Pragma("unroll")                                                        \
    for (int n_ = 0; n_ < 2; n_++) {                                         \
      bR[(nlo_) + n_][0] = *(const bf16x8*)((Bd_) + bhalf + ((nlo_) + n_) * 1024 + aoff + co0); \
      bR[(nlo_) + n_][1] = *(const bf16x8*)((Bd_) + bhalf + ((nlo_) + n_) * 1024 + aoff + co1); \
    } }
#define MFMA16(mb_, nl_) {                                                   \
    __builtin_amdgcn_s_setprio(1);                                           \
    _Pragma("unroll")                                                        \
    for (int m_ = 0; m_ < 4; m_++)                                           \
      _Pragma("unroll")                                                      \
      for (int n_ = 0; n_ < 2; n_++) {                                       \
        acc[(mb_) + m_][(nl_) + n_] =                                        \
            mfma16(aR[m_][0], bR[(nl_) + n_][0], acc[(mb_) + m_][(nl_) + n_]); \
        acc[(mb_) + m_][(nl_) + n_] =                                        \
            mfma16(aR[m_][1], bR[(nl_) + n_][1], acc[(mb_) + m_][(nl_) + n_]); \
      }                                                                      \
    __builtin_amdgcn_s_setprio(0); }

#define LGKM0 { asm volatile("s_waitcnt lgkmcnt(0)" ::: "memory");           \
                __builtin_amdgcn_sched_barrier(0); }
#define BAR   { asm volatile("s_barrier" ::: "memory"); }

// one K-tile = 4 phases, m201 order (stage before barrier, lgkm after).
#define KTILE(kt_, DOB, DOA, DOVM, VMq3) {                                   \
    const unsigned short* Ad = LA + wr * 8192 + ((kt_) & 1) * 16384;         \
    const unsigned short* Bd = LB + (wc >> 1) * 8192 + ((kt_) & 1) * 16384;  \
    /* q0 */                                                                 \
    RD_A(Ad, 0); RD_B(Bd, 0);                                                \
    if (DOB) STGB((kt_) + 1, 0);                                             \
    BAR; LGKM0;                                                              \
    MFMA16(0, 0); BAR;                                                       \
    /* q1 */                                                                 \
    RD_B(Bd, 2);                                                             \
    if (DOB) STGB((kt_) + 1, 1);                                             \
    BAR; LGKM0;                                                              \
    MFMA16(0, 2); BAR;                                                       \
    /* q2 */                                                                 \
    RD_A(Ad, 4);                                                             \
    BAR; LGKM0;                                                              \
    MFMA16(4, 0); BAR;                                                       \
    /* q3: no ds_read; stage A(kt+2); MFMA; vmcnt before the barrier */      \
    if (DOA) { STGA((kt_) + 2, 0); STGA((kt_) + 2, 1); }                     \
    MFMA16(4, 2);                                                            \
    if (DOVM) { asm volatile("s_waitcnt vmcnt(" VMq3 ")" ::: "memory"); }    \
    BAR; }

  // prologue: A(0), B(0), A(1) staged; confirm A(0)+B(0) (A(1) stays in flight)
  STGA(0, 0); STGA(0, 1);
  STGB(0, 0); STGB(0, 1);
  STGA(1, 0); STGA(1, 1);
  asm volatile("s_waitcnt vmcnt(4)" ::: "memory");
  BAR;

#pragma unroll 1
  for (int kt = 0; kt < 14; ++kt) {
    KTILE(kt, 1, 1, 1, "4");
  }
  KTILE(14, 1, 0, 1, "0");
  KTILE(15, 0, 0, 0, "0");

#undef KTILE
#undef BAR
#undef LGKM0
#undef MFMA16
#undef RD_B
#undef RD_A
#undef STGB
#undef STGA

  // epilogue: scatter into Q/K frag16x64, V -> V^T frag16x64
#pragma unroll
  for (int m = 0; m < 8; m++)
#pragma unroll
    for (int n = 0; n < 4; n++)
#pragma unroll
      for (int r = 0; r < 4; r++) {
        int row = m0 + wr * 128 + m * 16 + lg * 4 + r;
        int col = n0 + wc * 64 + n * 16 + lr;
        float v = acc[m][n][r] + bias[col];
        int bb = row >> 11, tl = row & 2047;
        if (col < Dc) {                                  // Q, scaled
          v *= 0.18033688f;                              // (1/8)*log2(e)
          int h = col >> 6, d = col & 63;
          Qf[(size_t)(bb * 16 + h) * 131072 + fragaddr(tl, d)] = f2bf(v);
        } else if (col < 2 * Dc) {                       // K
          int c = col - Dc, h = c >> 6, d = c & 63;
          Kf[(size_t)(bb * 16 + h) * 131072 + fragaddr(tl, d)] = f2bf(v);
        } else {                                         // V -> V^T frag
          int c = col - 2 * Dc, h = c >> 6, d = c & 63;
          Vf[(size_t)(bb * 16 + h) * 131072 + (tl >> 6) * 4096 + fragaddr(d, tl & 63)] = f2bf(v);
        }
      }
}

// ---------------------------------------------------------------------------
// gemm_bt (verified 128x128 structure) -- output projection, fp32 out.
// ---------------------------------------------------------------------------
__global__ __launch_bounds__(256) void gemm_bt(const unsigned short* __restrict__ A,
                                               const unsigned short* __restrict__ Bt,
                                               const float* __restrict__ bias,
                                               float* __restrict__ Cout,
                                               int N, int K) {
  __shared__ unsigned short As[128 * 64];
  __shared__ unsigned short Bs[128 * 64];
  const int tid = threadIdx.x;
  const int lane = tid & 63, wid = tid >> 6;
  const int lr = lane & 15, lg = lane >> 4;
  const int wrow = wid >> 1, wcol = wid & 1;
  const int m0 = blockIdx.y * 128, n0 = blockIdx.x * 128;

  f32x4 acc[4][4] = {};

  for (int k0 = 0; k0 < K; k0 += 64) {
#pragma unroll
    for (int i = 0; i < 4; i++) {
      int ci = i * 256 + tid;
      int row = ci >> 3, ph = ci & 7;
      int cl = ph ^ (row & 7);
      gload_lds16(A + (size_t)(m0 + row) * K + k0 + cl * 8, As + (size_t)(i * 256 + wid * 64) * 8);
      gload_lds16(Bt + (size_t)(n0 + row) * K + k0 + cl * 8, Bs + (size_t)(i * 256 + wid * 64) * 8);
    }
    asm volatile("s_waitcnt vmcnt(0)" ::: "memory");
    __syncthreads();
#pragma unroll
    for (int kk = 0; kk < 2; kk++) {
      bf16x8 av[4], bv[4];
#pragma unroll
      for (int m = 0; m < 4; m++) {
        int row = wrow * 64 + m * 16 + lr;
        int ph = (kk * 4 + lg) ^ (row & 7);
        av[m] = *(const bf16x8*)(As + row * 64 + ph * 8);
      }
#pragma unroll
      for (int n = 0; n < 4; n++) {
        int row = wcol * 64 + n * 16 + lr;
        int ph = (kk * 4 + lg) ^ (row & 7);
        bv[n] = *(const bf16x8*)(Bs + row * 64 + ph * 8);
      }
#pragma unroll
      for (int m = 0; m < 4; m++)
#pragma unroll
        for (int n = 0; n < 4; n++)
          acc[m][n] = mfma16(av[m], bv[n], acc[m][n]);
    }
    __syncthreads();
  }

#pragma unroll
  for (int m = 0; m < 4; m++)
#pragma unroll
    for (int n = 0; n < 4; n++)
#pragma unroll
      for (int r = 0; r < 4; r++) {
        int row = m0 + wrow * 64 + m * 16 + lg * 4 + r;
        int col = n0 + wcol * 64 + n * 16 + lr;
        Cout[(size_t)row * N + col] = acc[m][n][r] + bias[col];
      }
}

// ---------------------------------------------------------------------------
// flash7 (byte-identical to verified round-9 kernel)
// ---------------------------------------------------------------------------
__global__ __launch_bounds__(256, 2) void flash7(const unsigned short* __restrict__ Qf,
                                                 const unsigned short* __restrict__ Kf,
                                                 const unsigned short* __restrict__ Vf,
                                                 const int* __restrict__ mask,
                                                 unsigned short* __restrict__ merged) {
  const int tid = threadIdx.x;
  const int lane = tid & 63, wid = tid >> 6;
  const int lr = lane & 15, lg = lane >> 4;

  // XCD-bijective swizzle: 8 q-blocks of one head land on one XCD.
  const int lin = blockIdx.y * 8 + blockIdx.x;      // 0..511
  const int swz = (lin & 7) * 64 + (lin >> 3);
  const int qb = swz & 7, bh = swz >> 3;
  const int b = bh >> 4, h = bh & 15;
  const int wq = qb * 256 + wid * 64;               // wave's q base

  const unsigned short* Qb = Qf + (size_t)bh * 131072;
  const unsigned short* Kb = Kf + (size_t)bh * 131072;
  const unsigned short* Vb = Vf + (size_t)bh * 131072;

  bf16x8 qf[4][2];
#pragma unroll
  for (int qn = 0; qn < 4; qn++)
#pragma unroll
    for (int kk = 0; kk < 2; kk++)
      qf[qn][kk] = *(const bf16x8*)(Qb + ((wq >> 4) + qn) * 1024 + kk * 512 + lane * 8);

  f32x4 o[4][4] = {};
  f32x4 lacc[4] = {};

  bf16x8 ones;
#pragma unroll
  for (int j = 0; j < 8; j++) ones[j] = (bf16_t)1.0f;

  // whole-mask all-ones check (8 coalesced int4 loads), hoisted
  bool allone = true;
#pragma unroll
  for (int j = 0; j < 8; j++) {
    int4 mv = ((const int4*)mask)[j * 64 + lane];
    allone = allone && (mv.x != 0) && (mv.y != 0) && (mv.z != 0) && (mv.w != 0);
  }
  const bool nomask = (__ballot(allone) == ~0ull);

#pragma unroll 2
  for (int tile = 0; tile < 32; tile++) {
    bf16x8 kf[4][2];
#pragma unroll
    for (int n = 0; n < 4; n++)
#pragma unroll
      for (int kk = 0; kk < 2; kk++)
        kf[n][kk] = *(const bf16x8*)(Kb + (tile * 4 + n) * 1024 + kk * 512 + lane * 8);
    bf16x8 vf[4][2];
#pragma unroll
    for (int dn = 0; dn < 4; dn++)
#pragma unroll
      for (int kk = 0; kk < 2; kk++)
        vf[dn][kk] = *(const bf16x8*)(Vb + tile * 4096 + dn * 1024 + kk * 512 + lane * 8);

    unsigned long long mb = ~0ull;
    if (!nomask) mb = __ballot(mask[tile * 64 + lane] != 0);

    unsigned pk[4][4][2];
#pragma unroll
    for (int kvn = 0; kvn < 4; kvn++) {
      f32x4 st[4] = {};
#pragma unroll
      for (int qn = 0; qn < 4; qn++) {
        st[qn] = mfma16(kf[kvn][0], qf[qn][0], st[qn]);
        st[qn] = mfma16(kf[kvn][1], qf[qn][1], st[qn]);
      }
      if (mb != ~0ull) {
#pragma unroll
        for (int r = 0; r < 4; r++)
          if (!((mb >> (kvn * 16 + lg * 4 + r)) & 1ull)) {
#pragma unroll
            for (int qn = 0; qn < 4; qn++) st[qn][r] = -1e30f;
          }
      }
#pragma unroll
      for (int qn = 0; qn < 4; qn++) {
        float e[4];
#pragma unroll
        for (int r = 0; r < 4; r++)
          asm("v_exp_f32 %0, %1" : "=v"(e[r]) : "v"(st[qn][r]));
        asm("v_cvt_pk_bf16_f32 %0, %1, %2" : "=v"(pk[qn][kvn][0]) : "v"(e[0]), "v"(e[1]));
        asm("v_cvt_pk_bf16_f32 %0, %1, %2" : "=v"(pk[qn][kvn][1]) : "v"(e[2]), "v"(e[3]));
      }
    }

    bf16x8 pa[4][2];
#pragma unroll
    for (int qn = 0; qn < 4; qn++)
#pragma unroll
      for (int m = 0; m < 2; m++) {
        unsigned a0 = pk[qn][2 * m][0], b0 = pk[qn][2 * m + 1][0];
        unsigned a1 = pk[qn][2 * m][1], b1 = pk[qn][2 * m + 1][1];
        pl32swap(a0, b0);
        pl32swap(a1, b1);
        pl16swap(a0, b0);
        pl16swap(a1, b1);
        u32x4 w = { a0, a1, b0, b1 };
        pa[qn][m] = __builtin_bit_cast(bf16x8, w);
      }

    __builtin_amdgcn_s_setprio(1);
#pragma unroll
    for (int qn = 0; qn < 4; qn++) {
#pragma unroll
      for (int dn = 0; dn < 4; dn++) {
        o[qn][dn] = mfma16(pa[qn][0], vf[dn][0], o[qn][dn]);
        o[qn][dn] = mfma16(pa[qn][1], vf[dn][1], o[qn][dn]);
      }
      lacc[qn] = mfma16(pa[qn][0], ones, lacc[qn]);
      lacc[qn] = mfma16(pa[qn][1], ones, lacc[qn]);
    }
    __builtin_amdgcn_s_setprio(0);
  }

#pragma unroll
  for (int qn = 0; qn < 4; qn++)
#pragma unroll
    for (int r = 0; r < 4; r++) {
      float inv = 1.0f / lacc[qn][r];
      int grow = b * Tc + wq + qn * 16 + lg * 4 + r;
#pragma unroll
      for (int dn = 0; dn < 4; dn++) {
        int gcol = h * HDc + dn * 16 + lr;
        merged[(size_t)grow * Dc + gcol] = f2bf(o[qn][dn][r] * inv);
      }
    }
}

// ---------------------------------------------------------------------------
extern "C" void kernel_launch(void* const* d_in, const int* in_sizes, int n_in,
                              void* d_out, int out_size, void* d_ws, size_t ws_size,
                              hipStream_t stream) {
  const float* embed = (const float*)d_in[0];
  const int*   mask  = (const int*)d_in[1];
  const float* Wq = (const float*)d_in[2];
  const float* bq = (const float*)d_in[3];
  const float* Wk = (const float*)d_in[4];
  const float* bk = (const float*)d_in[5];
  const float* Wv = (const float*)d_in[6];
  const float* bv = (const float*)d_in[7];
  const float* Wo = (const float*)d_in[8];
  const float* bo = (const float*)d_in[9];
  float* out = (float*)d_out;

  char* ws = (char*)d_ws;
  unsigned short* embed_bf = (unsigned short*)ws; ws += (size_t)Mc * Dc * 2;        // 16.8 MB
  unsigned short* WtAll    = (unsigned short*)ws; ws += (size_t)4 * Dc * Dc * 2;    //  8.4 MB
  float*          ball     = (float*)ws;          ws += 16384;
  unsigned short* Qf       = (unsigned short*)ws; ws += (size_t)Mc * Dc * 2;        // 16.8 MB
  unsigned short* Kf       = (unsigned short*)ws; ws += (size_t)Mc * Dc * 2;        // 16.8 MB
  unsigned short* Vf       = (unsigned short*)ws; ws += (size_t)Mc * Dc * 2;        // 16.8 MB
  unsigned short* merged   = (unsigned short*)ws; ws += (size_t)Mc * Dc * 2;        // 16.8 MB

  prep<<<8192 + 1024 + 1, 256, 0, stream>>>(embed, Wq, Wk, Wv, Wo, bq, bk, bv,
                                            embed_bf, WtAll, ball);
  gemm_qkv10<<<dim3(12, 32), 512, 0, stream>>>(embed_bf, WtAll, ball, Qf, Kf, Vf);
  flash7<<<dim3(8, 64), 256, 0, stream>>>(Qf, Kf, Vf, mask, merged);
  gemm_bt<<<dim3(8, 64), 256, 0, stream>>>(merged, WtAll + (size_t)3 * Dc * Dc, bo, out, Dc, Dc);
}

// Round 12
// 192.629 us; speedup vs baseline: 1.0295x; 1.0133x over previous
//
#include <hip/hip_runtime.h>

// ---------------------------------------------------------------------------
// SelfAttention (B=4,T=2048,D=1024,H=16,hd=64) fp32 in/out, bf16 MFMA compute.
// Pipeline (4 kernels): prep -> gemm_qkv8 (256x256 tile, BK=32, 4 LDS bufs,
// counted-vmcnt pipeline, conflict-free 4-chunk swizzle) -> flash7 -> out gemm.
//
// frag16x64 layout: matrix [R][64] stored per 16-row block:
//   addr(row,col) = (row>>4)*1024 + (col>>5)*512 + ((col>>3)&3)*128
//                 + (row&15)*8 + (col&7)
// ---------------------------------------------------------------------------

typedef __bf16 bf16_t;
typedef bf16_t bf16x8 __attribute__((ext_vector_type(8)));
typedef float  f32x4  __attribute__((ext_vector_type(4)));
typedef unsigned u32x4 __attribute__((ext_vector_type(4)));
typedef unsigned short u16x8 __attribute__((ext_vector_type(8)));
typedef unsigned short u16x4 __attribute__((ext_vector_type(4)));

#define DEV static __device__ __forceinline__

constexpr int Bc = 4, Tc = 2048, Dc = 1024, Hc = 16, HDc = 64;
constexpr int Mc = Bc * Tc;        // 8192 rows
constexpr int NQKV = 3 * Dc;       // 3072

DEV unsigned short f2bf(float f) {
  union { float f; unsigned u; } v; v.f = f;
  return (unsigned short)((v.u + 0x7fffu + ((v.u >> 16) & 1u)) >> 16);
}

DEV void gload_lds16(const void* g, const void* ldsbase) {
  unsigned m0v = __builtin_amdgcn_readfirstlane((unsigned)(unsigned long long)ldsbase);
  asm volatile("s_mov_b32 m0, %0\n\t"
               "global_load_lds_dwordx4 %1, off"
               :: "s"(m0v), "v"(g) : "memory");
}

DEV f32x4 mfma16(bf16x8 a, bf16x8 b, f32x4 c) {
  return __builtin_amdgcn_mfma_f32_16x16x32_bf16(a, b, c, 0, 0, 0);
}

DEV void pl32swap(unsigned& a, unsigned& b) {
  asm("v_permlane32_swap_b32 %0, %1" : "+v"(a), "+v"(b));
}
DEV void pl16swap(unsigned& a, unsigned& b) {
  asm("v_permlane16_swap_b32 %0, %1" : "+v"(a), "+v"(b));
}

// frag16x64 element address (row within a [R][64] matrix)
DEV int fragaddr(int row, int col) {
  return (row >> 4) * 1024 + ((col >> 5) << 9) + (((col >> 3) & 3) << 7)
       + ((row & 15) << 3) + (col & 7);
}

// ---------------------------------------------------------------------------
// prep: fused cvt_embed (blocks 0..8191) + wt_cvt (8192..9215) + bias (9216)
// ---------------------------------------------------------------------------
__global__ __launch_bounds__(256) void prep(const float* __restrict__ embed,
                                            const float* __restrict__ Wq,
                                            const float* __restrict__ Wk,
                                            const float* __restrict__ Wv,
                                            const float* __restrict__ Wo,
                                            const float* __restrict__ bq,
                                            const float* __restrict__ bk,
                                            const float* __restrict__ bv,
                                            unsigned short* __restrict__ embed_bf,
                                            unsigned short* __restrict__ WtAll,
                                            float* __restrict__ ball) {
  __shared__ unsigned short tile[64 * 80];
  const int bb = blockIdx.x;
  const int tid = threadIdx.x;

  if (bb < 8192) {                                   // ---- embed f32 -> bf16
    int i = bb * 256 + tid;
    float4 v = ((const float4*)embed)[i];
    u16x4 o = { f2bf(v.x), f2bf(v.y), f2bf(v.z), f2bf(v.w) };
    *(u16x4*)(embed_bf + (size_t)i * 4) = o;
    return;
  }
  if (bb < 8192 + 1024) {                            // ---- W -> W^T bf16
    int wb = bb - 8192;
    int bx = wb & 15, by = (wb >> 4) & 15, bz = wb >> 8;
    const float* W = bz == 0 ? Wq : bz == 1 ? Wk : bz == 2 ? Wv : Wo;
    unsigned short* dst = WtAll + (size_t)bz * 1024 * 1024;
    const int kb = by * 64, nb = bx * 64;
#pragma unroll
    for (int i = 0; i < 4; i++) {
      int ci = i * 256 + tid;
      int r = ci >> 4, c4 = ci & 15;
      float4 v = *(const float4*)(W + (size_t)(kb + r) * 1024 + nb + c4 * 4);
      u16x4 o = { f2bf(v.x), f2bf(v.y), f2bf(v.z), f2bf(v.w) };
      *(u16x4*)(tile + r * 80 + c4 * 4) = o;
    }
    __syncthreads();
#pragma unroll
    for (int i = 0; i < 2; i++) {
      int ci = i * 256 + tid;
      int n = ci >> 3, c8 = ci & 7;
      u16x8 o;
#pragma unroll
      for (int j = 0; j < 8; j++) o[j] = tile[(c8 * 8 + j) * 80 + n];
      *(u16x8*)(dst + (size_t)(nb + n) * 1024 + kb + c8 * 8) = o;
    }
    return;
  }
  // ---- bias concat (single block)
#pragma unroll
  for (int it = 0; it < 12; it++) {
    int i = it * 256 + tid;
    ball[i] = (i < 1024) ? bq[i] : (i < 2048) ? bk[i - 1024] : bv[i - 2048];
  }
}

// ---------------------------------------------------------------------------
// gemm_qkv8: QKV projection, 256x256 block tile, BK=32, counted-vmcnt
// pipeline (verified round-8 structure). 512 threads = 8 waves (2M x 4N),
// wave-tile 128x64. 4 LDS buffers per operand (32 KB each, 128 KB total).
// K-tile kt in buf kt&3; staged 3 ahead; s_waitcnt vmcnt(8) per tile.
// Swizzle (改): phys_chunk = logical ^ ((row ^ (row>>2)) & 3) — folds row
// bit-2 so even-lr lanes spread over 4 slots (old row&3 gave 4-way conflicts,
// 4.7M/dispatch). Same involution on stage-source and read side.
// Epilogue: Q (scaled 0.125*log2e) / K -> frag16x64; V -> V^T frag16x64.
// ---------------------------------------------------------------------------
__global__ __launch_bounds__(512, 2) void gemm_qkv8(
    const unsigned short* __restrict__ A,      // embed_bf [8192][1024]
    const unsigned short* __restrict__ Bt,     // WtAll    [3072][1024]
    const float* __restrict__ bias,            // ball[3072]
    unsigned short* __restrict__ Qf,
    unsigned short* __restrict__ Kf,
    unsigned short* __restrict__ Vf) {
  __shared__ unsigned short As_[4 * 8192];     // 64 KB
  __shared__ unsigned short Bs_[4 * 8192];     // 64 KB

  const int tid = threadIdx.x;
  const int lane = tid & 63, wid = tid >> 6;
  const int lr = lane & 15, lg = lane >> 4;
  const int wr = wid >> 2, wc = wid & 3;

  // grid (12 N, 32 M); XCD-bijective swizzle: each XCD gets 4 M-panels x all N
  const int lin = blockIdx.y * 12 + blockIdx.x;        // 0..383
  const int swz = (lin & 7) * 48 + (lin >> 3);
  const int m0 = (swz / 12) * 256, n0 = (swz % 12) * 256;

  // staging constants: ci = i*512+tid; row=ci>>2; cl = (ci&3)^s(row),
  // s(row) = (row ^ (row>>2)) & 3
  size_t gA[2], gB[2];
  int ldsoff[2];
#pragma unroll
  for (int i = 0; i < 2; i++) {
    int ci = i * 512 + tid;
    int row = ci >> 2;
    int cl = (ci & 3) ^ ((row ^ (row >> 2)) & 3);
    gA[i] = (size_t)(m0 + row) * 1024 + cl * 8;
    gB[i] = (size_t)(n0 + row) * 1024 + cl * 8;
    ldsoff[i] = ci * 8;
  }

  // ds-read element offsets (within one 8192-elem buffer)
  int offA[2][4], offB[4];
#pragma unroll
  for (int mq = 0; mq < 2; mq++)
#pragma unroll
    for (int m = 0; m < 4; m++) {
      int row = wr * 128 + mq * 64 + m * 16 + lr;
      offA[mq][m] = row * 32 + ((lg ^ ((row ^ (row >> 2)) & 3)) << 3);
    }
#pragma unroll
  for (int n = 0; n < 4; n++) {
    int row = wc * 64 + n * 16 + lr;
    offB[n] = row * 32 + ((lg ^ ((row ^ (row >> 2)) & 3)) << 3);
  }

  f32x4 acc[8][4] = {};

#define QSTAGE(kt) {                                                         \
    const int sbi_ = (kt) & 3;                                               \
    _Pragma("unroll")                                                        \
    for (int i_ = 0; i_ < 2; i_++) {                                         \
      gload_lds16(A  + gA[i_] + (size_t)(kt) * 32,                           \
                  As_ + sbi_ * 8192 + ldsoff[i_]);                           \
      gload_lds16(Bt + gB[i_] + (size_t)(kt) * 32,                           \
                  Bs_ + sbi_ * 8192 + ldsoff[i_]);                           \
    } }

#define QKTILE(kt, VM, DOST) {                                               \
    const int bi_ = (kt) & 3;                                                \
    const unsigned short* Ab = As_ + bi_ * 8192;                             \
    const unsigned short* Bb = Bs_ + bi_ * 8192;                             \
    asm volatile("s_waitcnt vmcnt(" VM ")" ::: "memory");                    \
    asm volatile("s_barrier" ::: "memory");                                  \
    bf16x8 a0 = *(const bf16x8*)(Ab + offA[0][0]);                           \
    bf16x8 a1 = *(const bf16x8*)(Ab + offA[0][1]);                           \
    bf16x8 a2 = *(const bf16x8*)(Ab + offA[0][2]);                           \
    bf16x8 a3 = *(const bf16x8*)(Ab + offA[0][3]);                           \
    bf16x8 b0 = *(const bf16x8*)(Bb + offB[0]);                              \
    bf16x8 b1 = *(const bf16x8*)(Bb + offB[1]);                              \
    bf16x8 b2 = *(const bf16x8*)(Bb + offB[2]);                              \
    bf16x8 b3 = *(const bf16x8*)(Bb + offB[3]);                              \
    if (DOST) QSTAGE((kt) + 3);                                              \
    __builtin_amdgcn_s_setprio(1);                                           \
    acc[0][0]=mfma16(a0,b0,acc[0][0]); acc[0][1]=mfma16(a0,b1,acc[0][1]);    \
    acc[0][2]=mfma16(a0,b2,acc[0][2]); acc[0][3]=mfma16(a0,b3,acc[0][3]);    \
    acc[1][0]=mfma16(a1,b0,acc[1][0]); acc[1][1]=mfma16(a1,b1,acc[1][1]);    \
    acc[1][2]=mfma16(a1,b2,acc[1][2]); acc[1][3]=mfma16(a1,b3,acc[1][3]);    \
    acc[2][0]=mfma16(a2,b0,acc[2][0]); acc[2][1]=mfma16(a2,b1,acc[2][1]);    \
    acc[2][2]=mfma16(a2,b2,acc[2][2]); acc[2][3]=mfma16(a2,b3,acc[2][3]);    \
    acc[3][0]=mfma16(a3,b0,acc[3][0]); acc[3][1]=mfma16(a3,b1,acc[3][1]);    \
    acc[3][2]=mfma16(a3,b2,acc[3][2]); acc[3][3]=mfma16(a3,b3,acc[3][3]);    \
    __builtin_amdgcn_s_setprio(0);                                           \
    a0 = *(const bf16x8*)(Ab + offA[1][0]);                                  \
    a1 = *(const bf16x8*)(Ab + offA[1][1]);                                  \
    a2 = *(const bf16x8*)(Ab + offA[1][2]);                                  \
    a3 = *(const bf16x8*)(Ab + offA[1][3]);                                  \
    __builtin_amdgcn_s_setprio(1);                                           \
    acc[4][0]=mfma16(a0,b0,acc[4][0]); acc[4][1]=mfma16(a0,b1,acc[4][1]);    \
    acc[4][2]=mfma16(a0,b2,acc[4][2]); acc[4][3]=mfma16(a0,b3,acc[4][3]);    \
    acc[5][0]=mfma16(a1,b0,acc[5][0]); acc[5][1]=mfma16(a1,b1,acc[5][1]);    \
    acc[5][2]=mfma16(a1,b2,acc[5][2]); acc[5][3]=mfma16(a1,b3,acc[5][3]);    \
    acc[6][0]=mfma16(a2,b0,acc[6][0]); acc[6][1]=mfma16(a2,b1,acc[6][1]);    \
    acc[6][2]=mfma16(a2,b2,acc[6][2]); acc[6][3]=mfma16(a2,b3,acc[6][3]);    \
    acc[7][0]=mfma16(a3,b0,acc[7][0]); acc[7][1]=mfma16(a3,b1,acc[7][1]);    \
    acc[7][2]=mfma16(a3,b2,acc[7][2]); acc[7][3]=mfma16(a3,b3,acc[7][3]);    \
    __builtin_amdgcn_s_setprio(0); }

  // prologue: 3 K-tiles in flight
  QSTAGE(0); QSTAGE(1); QSTAGE(2);

#pragma unroll 1
  for (int kt = 0; kt < 29; ++kt) {
    QKTILE(kt, "8", 1);
  }
  QKTILE(29, "8", 0);
  QKTILE(30, "4", 0);
  QKTILE(31, "0", 0);
#undef QSTAGE
#undef QKTILE

  // epilogue: scatter into Q/K frag16x64, V -> V^T frag16x64
#pragma unroll
  for (int mq = 0; mq < 8; mq++)
#pragma unroll
    for (int n = 0; n < 4; n++)
#pragma unroll
      for (int r = 0; r < 4; r++) {
        int row = m0 + wr * 128 + (mq >> 2) * 64 + (mq & 3) * 16 + lg * 4 + r;
        int col = n0 + wc * 64 + n * 16 + lr;
        float v = acc[mq][n][r] + bias[col];
        int bb = row >> 11, tl = row & 2047;
        if (col < Dc) {                                  // Q, scaled
          v *= 0.18033688f;                              // (1/8)*log2(e)
          int h = col >> 6, d = col & 63;
          Qf[(size_t)(bb * 16 + h) * 131072 + fragaddr(tl, d)] = f2bf(v);
        } else if (col < 2 * Dc) {                       // K
          int c = col - Dc, h = c >> 6, d = c & 63;
          Kf[(size_t)(bb * 16 + h) * 131072 + fragaddr(tl, d)] = f2bf(v);
        } else {                                         // V -> V^T frag
          int c = col - 2 * Dc, h = c >> 6, d = c & 63;
          Vf[(size_t)(bb * 16 + h) * 131072 + (tl >> 6) * 4096 + fragaddr(d, tl & 63)] = f2bf(v);
        }
      }
}

// ---------------------------------------------------------------------------
// gemm_bt (verified 128x128 structure) -- output projection, fp32 out.
// ---------------------------------------------------------------------------
__global__ __launch_bounds__(256) void gemm_bt(const unsigned short* __restrict__ A,
                                               const unsigned short* __restrict__ Bt,
                                               const float* __restrict__ bias,
                                               float* __restrict__ Cout,
                                               int N, int K) {
  __shared__ unsigned short As[128 * 64];
  __shared__ unsigned short Bs[128 * 64];
  const int tid = threadIdx.x;
  const int lane = tid & 63, wid = tid >> 6;
  const int lr = lane & 15, lg = lane >> 4;
  const int wrow = wid >> 1, wcol = wid & 1;
  const int m0 = blockIdx.y * 128, n0 = blockIdx.x * 128;

  f32x4 acc[4][4] = {};

  for (int k0 = 0; k0 < K; k0 += 64) {
#pragma unroll
    for (int i = 0; i < 4; i++) {
      int ci = i * 256 + tid;
      int row = ci >> 3, ph = ci & 7;
      int cl = ph ^ (row & 7);
      gload_lds16(A + (size_t)(m0 + row) * K + k0 + cl * 8, As + (size_t)(i * 256 + wid * 64) * 8);
      gload_lds16(Bt + (size_t)(n0 + row) * K + k0 + cl * 8, Bs + (size_t)(i * 256 + wid * 64) * 8);
    }
    asm volatile("s_waitcnt vmcnt(0)" ::: "memory");
    __syncthreads();
#pragma unroll
    for (int kk = 0; kk < 2; kk++) {
      bf16x8 av[4], bv[4];
#pragma unroll
      for (int m = 0; m < 4; m++) {
        int row = wrow * 64 + m * 16 + lr;
        int ph = (kk * 4 + lg) ^ (row & 7);
        av[m] = *(const bf16x8*)(As + row * 64 + ph * 8);
      }
#pragma unroll
      for (int n = 0; n < 4; n++) {
        int row = wcol * 64 + n * 16 + lr;
        int ph = (kk * 4 + lg) ^ (row & 7);
        bv[n] = *(const bf16x8*)(Bs + row * 64 + ph * 8);
      }
#pragma unroll
      for (int m = 0; m < 4; m++)
#pragma unroll
        for (int n = 0; n < 4; n++)
          acc[m][n] = mfma16(av[m], bv[n], acc[m][n]);
    }
    __syncthreads();
  }

#pragma unroll
  for (int m = 0; m < 4; m++)
#pragma unroll
    for (int n = 0; n < 4; n++)
#pragma unroll
      for (int r = 0; r < 4; r++) {
        int row = m0 + wrow * 64 + m * 16 + lg * 4 + r;
        int col = n0 + wcol * 64 + n * 16 + lr;
        Cout[(size_t)row * N + col] = acc[m][n][r] + bias[col];
      }
}

// ---------------------------------------------------------------------------
// flash7 (byte-identical to verified round-9 kernel)
// ---------------------------------------------------------------------------
__global__ __launch_bounds__(256, 2) void flash7(const unsigned short* __restrict__ Qf,
                                                 const unsigned short* __restrict__ Kf,
                                                 const unsigned short* __restrict__ Vf,
                                                 const int* __restrict__ mask,
                                                 unsigned short* __restrict__ merged) {
  const int tid = threadIdx.x;
  const int lane = tid & 63, wid = tid >> 6;
  const int lr = lane & 15, lg = lane >> 4;

  // XCD-bijective swizzle: 8 q-blocks of one head land on one XCD.
  const int lin = blockIdx.y * 8 + blockIdx.x;      // 0..511
  const int swz = (lin & 7) * 64 + (lin >> 3);
  const int qb = swz & 7, bh = swz >> 3;
  const int b = bh >> 4, h = bh & 15;
  const int wq = qb * 256 + wid * 64;               // wave's q base

  const unsigned short* Qb = Qf + (size_t)bh * 131072;
  const unsigned short* Kb = Kf + (size_t)bh * 131072;
  const unsigned short* Vb = Vf + (size_t)bh * 131072;

  bf16x8 qf[4][2];
#pragma unroll
  for (int qn = 0; qn < 4; qn++)
#pragma unroll
    for (int kk = 0; kk < 2; kk++)
      qf[qn][kk] = *(const bf16x8*)(Qb + ((wq >> 4) + qn) * 1024 + kk * 512 + lane * 8);

  f32x4 o[4][4] = {};
  f32x4 lacc[4] = {};

  bf16x8 ones;
#pragma unroll
  for (int j = 0; j < 8; j++) ones[j] = (bf16_t)1.0f;

  // whole-mask all-ones check (8 coalesced int4 loads), hoisted
  bool allone = true;
#pragma unroll
  for (int j = 0; j < 8; j++) {
    int4 mv = ((const int4*)mask)[j * 64 + lane];
    allone = allone && (mv.x != 0) && (mv.y != 0) && (mv.z != 0) && (mv.w != 0);
  }
  const bool nomask = (__ballot(allone) == ~0ull);

#pragma unroll 2
  for (int tile = 0; tile < 32; tile++) {
    bf16x8 kf[4][2];
#pragma unroll
    for (int n = 0; n < 4; n++)
#pragma unroll
      for (int kk = 0; kk < 2; kk++)
        kf[n][kk] = *(const bf16x8*)(Kb + (tile * 4 + n) * 1024 + kk * 512 + lane * 8);
    bf16x8 vf[4][2];
#pragma unroll
    for (int dn = 0; dn < 4; dn++)
#pragma unroll
      for (int kk = 0; kk < 2; kk++)
        vf[dn][kk] = *(const bf16x8*)(Vb + tile * 4096 + dn * 1024 + kk * 512 + lane * 8);

    unsigned long long mb = ~0ull;
    if (!nomask) mb = __ballot(mask[tile * 64 + lane] != 0);

    unsigned pk[4][4][2];
#pragma unroll
    for (int kvn = 0; kvn < 4; kvn++) {
      f32x4 st[4] = {};
#pragma unroll
      for (int qn = 0; qn < 4; qn++) {
        st[qn] = mfma16(kf[kvn][0], qf[qn][0], st[qn]);
        st[qn] = mfma16(kf[kvn][1], qf[qn][1], st[qn]);
      }
      if (mb != ~0ull) {
#pragma unroll
        for (int r = 0; r < 4; r++)
          if (!((mb >> (kvn * 16 + lg * 4 + r)) & 1ull)) {
#pragma unroll
            for (int qn = 0; qn < 4; qn++) st[qn][r] = -1e30f;
          }
      }
#pragma unroll
      for (int qn = 0; qn < 4; qn++) {
        float e[4];
#pragma unroll
        for (int r = 0; r < 4; r++)
          asm("v_exp_f32 %0, %1" : "=v"(e[r]) : "v"(st[qn][r]));
        asm("v_cvt_pk_bf16_f32 %0, %1, %2" : "=v"(pk[qn][kvn][0]) : "v"(e[0]), "v"(e[1]));
        asm("v_cvt_pk_bf16_f32 %0, %1, %2" : "=v"(pk[qn][kvn][1]) : "v"(e[2]), "v"(e[3]));
      }
    }

    bf16x8 pa[4][2];
#pragma unroll
    for (int qn = 0; qn < 4; qn++)
#pragma unroll
      for (int m = 0; m < 2; m++) {
        unsigned a0 = pk[qn][2 * m][0], b0 = pk[qn][2 * m + 1][0];
        unsigned a1 = pk[qn][2 * m][1], b1 = pk[qn][2 * m + 1][1];
        pl32swap(a0, b0);
        pl32swap(a1, b1);
        pl16swap(a0, b0);
        pl16swap(a1, b1);
        u32x4 w = { a0, a1, b0, b1 };
        pa[qn][m] = __builtin_bit_cast(bf16x8, w);
      }

    __builtin_amdgcn_s_setprio(1);
#pragma unroll
    for (int qn = 0; qn < 4; qn++) {
#pragma unroll
      for (int dn = 0; dn < 4; dn++) {
        o[qn][dn] = mfma16(pa[qn][0], vf[dn][0], o[qn][dn]);
        o[qn][dn] = mfma16(pa[qn][1], vf[dn][1], o[qn][dn]);
      }
      lacc[qn] = mfma16(pa[qn][0], ones, lacc[qn]);
      lacc[qn] = mfma16(pa[qn][1], ones, lacc[qn]);
    }
    __builtin_amdgcn_s_setprio(0);
  }

#pragma unroll
  for (int qn = 0; qn < 4; qn++)
#pragma unroll
    for (int r = 0; r < 4; r++) {
      float inv = 1.0f / lacc[qn][r];
      int grow = b * Tc + wq + qn * 16 + lg * 4 + r;
#pragma unroll
      for (int dn = 0; dn < 4; dn++) {
        int gcol = h * HDc + dn * 16 + lr;
        merged[(size_t)grow * Dc + gcol] = f2bf(o[qn][dn][r] * inv);
      }
    }
}

// ---------------------------------------------------------------------------
extern "C" void kernel_launch(void* const* d_in, const int* in_sizes, int n_in,
                              void* d_out, int out_size, void* d_ws, size_t ws_size,
                              hipStream_t stream) {
  const float* embed = (const float*)d_in[0];
  const int*   mask  = (const int*)d_in[1];
  const float* Wq = (const float*)d_in[2];
  const float* bq = (const float*)d_in[3];
  const float* Wk = (const float*)d_in[4];
  const float* bk = (const float*)d_in[5];
  const float* Wv = (const float*)d_in[6];
  const float* bv = (const float*)d_in[7];
  const float* Wo = (const float*)d_in[8];
  const float* bo = (const float*)d_in[9];
  float* out = (float*)d_out;

  char* ws = (char*)d_ws;
  unsigned short* embed_bf = (unsigned short*)ws; ws += (size_t)Mc * Dc * 2;        // 16.8 MB
  unsigned short* WtAll    = (unsigned short*)ws; ws += (size_t)4 * Dc * Dc * 2;    //  8.4 MB
  float*          ball     = (float*)ws;          ws += 16384;
  unsigned short* Qf       = (unsigned short*)ws; ws += (size_t)Mc * Dc * 2;        // 16.8 MB
  unsigned short* Kf       = (unsigned short*)ws; ws += (size_t)Mc * Dc * 2;        // 16.8 MB
  unsigned short* Vf       = (unsigned short*)ws; ws += (size_t)Mc * Dc * 2;        // 16.8 MB
  unsigned short* merged   = (unsigned short*)ws; ws += (size_t)Mc * Dc * 2;        // 16.8 MB

  prep<<<8192 + 1024 + 1, 256, 0, stream>>>(embed, Wq, Wk, Wv, Wo, bq, bk, bv,
                                            embed_bf, WtAll, ball);
  gemm_qkv8<<<dim3(12, 32), 512, 0, stream>>>(embed_bf, WtAll, ball, Qf, Kf, Vf);
  flash7<<<dim3(8, 64), 256, 0, stream>>>(Qf, Kf, Vf, mask, merged);
  gemm_bt<<<dim3(8, 64), 256, 0, stream>>>(merged, WtAll + (size_t)3 * Dc * Dc, bo, out, Dc, Dc);
}

// Round 13
// 177.575 us; speedup vs baseline: 1.1168x; 1.0848x over previous
//
#include <hip/hip_runtime.h>

// ---------------------------------------------------------------------------
// SelfAttention (B=4,T=2048,D=1024,H=16,hd=64) fp32 in/out, bf16 MFMA compute.
// Pipeline (4 kernels): prep -> gemm_qkv11 (operand-swapped 256x256 BK=32
// counted-vmcnt mainloop; Q/K epilogue = in-register relayout + coalesced
// frag16x64 stores, V = scatter) -> flash7 -> out gemm.
//
// frag16x64 layout: matrix [R][64] stored per 16-row block:
//   addr(row,col) = (row>>4)*1024 + (col>>5)*512 + ((col>>3)&3)*128
//                 + (row&15)*8 + (col&7)
// ---------------------------------------------------------------------------

typedef __bf16 bf16_t;
typedef bf16_t bf16x8 __attribute__((ext_vector_type(8)));
typedef float  f32x4  __attribute__((ext_vector_type(4)));
typedef unsigned u32x4 __attribute__((ext_vector_type(4)));
typedef unsigned short u16x8 __attribute__((ext_vector_type(8)));
typedef unsigned short u16x4 __attribute__((ext_vector_type(4)));

#define DEV static __device__ __forceinline__

constexpr int Bc = 4, Tc = 2048, Dc = 1024, Hc = 16, HDc = 64;
constexpr int Mc = Bc * Tc;        // 8192 rows
constexpr int NQKV = 3 * Dc;       // 3072

DEV unsigned short f2bf(float f) {
  union { float f; unsigned u; } v; v.f = f;
  return (unsigned short)((v.u + 0x7fffu + ((v.u >> 16) & 1u)) >> 16);
}

DEV void gload_lds16(const void* g, const void* ldsbase) {
  unsigned m0v = __builtin_amdgcn_readfirstlane((unsigned)(unsigned long long)ldsbase);
  asm volatile("s_mov_b32 m0, %0\n\t"
               "global_load_lds_dwordx4 %1, off"
               :: "s"(m0v), "v"(g) : "memory");
}

DEV f32x4 mfma16(bf16x8 a, bf16x8 b, f32x4 c) {
  return __builtin_amdgcn_mfma_f32_16x16x32_bf16(a, b, c, 0, 0, 0);
}

DEV void pl32swap(unsigned& a, unsigned& b) {
  asm("v_permlane32_swap_b32 %0, %1" : "+v"(a), "+v"(b));
}
DEV void pl16swap(unsigned& a, unsigned& b) {
  asm("v_permlane16_swap_b32 %0, %1" : "+v"(a), "+v"(b));
}

// frag16x64 element address (row within a [R][64] matrix)
DEV int fragaddr(int row, int col) {
  return (row >> 4) * 1024 + ((col >> 5) << 9) + (((col >> 3) & 3) << 7)
       + ((row & 15) << 3) + (col & 7);
}

// ---------------------------------------------------------------------------
// prep: fused cvt_embed (blocks 0..8191) + wt_cvt (8192..9215) + bias (9216)
// ---------------------------------------------------------------------------
__global__ __launch_bounds__(256) void prep(const float* __restrict__ embed,
                                            const float* __restrict__ Wq,
                                            const float* __restrict__ Wk,
                                            const float* __restrict__ Wv,
                                            const float* __restrict__ Wo,
                                            const float* __restrict__ bq,
                                            const float* __restrict__ bk,
                                            const float* __restrict__ bv,
                                            unsigned short* __restrict__ embed_bf,
                                            unsigned short* __restrict__ WtAll,
                                            float* __restrict__ ball) {
  __shared__ unsigned short tile[64 * 80];
  const int bb = blockIdx.x;
  const int tid = threadIdx.x;

  if (bb < 8192) {                                   // ---- embed f32 -> bf16
    int i = bb * 256 + tid;
    float4 v = ((const float4*)embed)[i];
    u16x4 o = { f2bf(v.x), f2bf(v.y), f2bf(v.z), f2bf(v.w) };
    *(u16x4*)(embed_bf + (size_t)i * 4) = o;
    return;
  }
  if (bb < 8192 + 1024) {                            // ---- W -> W^T bf16
    int wb = bb - 8192;
    int bx = wb & 15, by = (wb >> 4) & 15, bz = wb >> 8;
    const float* W = bz == 0 ? Wq : bz == 1 ? Wk : bz == 2 ? Wv : Wo;
    unsigned short* dst = WtAll + (size_t)bz * 1024 * 1024;
    const int kb = by * 64, nb = bx * 64;
#pragma unroll
    for (int i = 0; i < 4; i++) {
      int ci = i * 256 + tid;
      int r = ci >> 4, c4 = ci & 15;
      float4 v = *(const float4*)(W + (size_t)(kb + r) * 1024 + nb + c4 * 4);
      u16x4 o = { f2bf(v.x), f2bf(v.y), f2bf(v.z), f2bf(v.w) };
      *(u16x4*)(tile + r * 80 + c4 * 4) = o;
    }
    __syncthreads();
#pragma unroll
    for (int i = 0; i < 2; i++) {
      int ci = i * 256 + tid;
      int n = ci >> 3, c8 = ci & 7;
      u16x8 o;
#pragma unroll
      for (int j = 0; j < 8; j++) o[j] = tile[(c8 * 8 + j) * 80 + n];
      *(u16x8*)(dst + (size_t)(nb + n) * 1024 + kb + c8 * 8) = o;
    }
    return;
  }
  // ---- bias concat (single block)
#pragma unroll
  for (int it = 0; it < 12; it++) {
    int i = it * 256 + tid;
    ball[i] = (i < 1024) ? bq[i] : (i < 2048) ? bk[i - 1024] : bv[i - 2048];
  }
}

// ---------------------------------------------------------------------------
// gemm_qkv11: OPERAND-SWAPPED QKV projection. C'[f][t] = Wt[f][:]. embed[t][:]
// (= QKV[t][f]). 256(f) x 256(t) tile, BK=32, counted-vmcnt pipeline
// (qkv8's verified sync structure, A<->B sources swapped). 512 thr = 8 waves
// (2 f x 4 t), wave-tile 128f x 64t, acc[8][4]: f on (m,lg,r), t on (n,lr).
// Epilogue:
//   Q/K blocks (feature-tile < 8): token stays lane-local -> reuse flash's
//   VERIFIED relayout (cvt_pk pairs + pl32swap + pl16swap, kvn->mq, q->t)
//   to produce frag16x64 Q/K-frags -> 16B/lane coalesced stores.
//   V blocks: existing scatter path (V^T frag16x64).
// ---------------------------------------------------------------------------
__global__ __launch_bounds__(512, 2) void gemm_qkv11(
    const unsigned short* __restrict__ Wt,     // WtAll    [3072][1024]
    const unsigned short* __restrict__ Eb,     // embed_bf [8192][1024]
    const float* __restrict__ bias,            // ball[3072]
    unsigned short* __restrict__ Qf,
    unsigned short* __restrict__ Kf,
    unsigned short* __restrict__ Vf) {
  __shared__ unsigned short As_[4 * 8192];     // 64 KB (Wt rows)
  __shared__ unsigned short Bs_[4 * 8192];     // 64 KB (embed rows)

  const int tid = threadIdx.x;
  const int lane = tid & 63, wid = tid >> 6;
  const int lr = lane & 15, lg = lane >> 4;
  const int wr = wid >> 2, wc = wid & 3;

  // grid (12,32); XCD-bijective swizzle. m0 = feature base, n0 = token base.
  const int lin = blockIdx.y * 12 + blockIdx.x;        // 0..383
  const int swz = (lin & 7) * 48 + (lin >> 3);
  const int m0 = (swz % 12) * 256, n0 = (swz / 12) * 256;

  size_t gA[2], gB[2];
  int ldsoff[2];
#pragma unroll
  for (int i = 0; i < 2; i++) {
    int ci = i * 512 + tid;
    int row = ci >> 2;
    int cl = (ci & 3) ^ ((row ^ (row >> 2)) & 3);
    gA[i] = (size_t)(m0 + row) * 1024 + cl * 8;        // Wt rows (features)
    gB[i] = (size_t)(n0 + row) * 1024 + cl * 8;        // embed rows (tokens)
    ldsoff[i] = ci * 8;
  }

  int offA[2][4], offB[4];
#pragma unroll
  for (int mq = 0; mq < 2; mq++)
#pragma unroll
    for (int m = 0; m < 4; m++) {
      int row = wr * 128 + mq * 64 + m * 16 + lr;
      offA[mq][m] = row * 32 + ((lg ^ ((row ^ (row >> 2)) & 3)) << 3);
    }
#pragma unroll
  for (int n = 0; n < 4; n++) {
    int row = wc * 64 + n * 16 + lr;
    offB[n] = row * 32 + ((lg ^ ((row ^ (row >> 2)) & 3)) << 3);
  }

  f32x4 acc[8][4] = {};

#define QSTAGE(kt) {                                                         \
    const int sbi_ = (kt) & 3;                                               \
    _Pragma("unroll")                                                        \
    for (int i_ = 0; i_ < 2; i_++) {                                         \
      gload_lds16(Wt + gA[i_] + (size_t)(kt) * 32,                           \
                  As_ + sbi_ * 8192 + ldsoff[i_]);                           \
      gload_lds16(Eb + gB[i_] + (size_t)(kt) * 32,                           \
                  Bs_ + sbi_ * 8192 + ldsoff[i_]);                           \
    } }

#define QKTILE(kt, VM, DOST) {                                               \
    const int bi_ = (kt) & 3;                                                \
    const unsigned short* Ab = As_ + bi_ * 8192;                             \
    const unsigned short* Bb = Bs_ + bi_ * 8192;                             \
    asm volatile("s_waitcnt vmcnt(" VM ")" ::: "memory");                    \
    asm volatile("s_barrier" ::: "memory");                                  \
    bf16x8 a0 = *(const bf16x8*)(Ab + offA[0][0]);                           \
    bf16x8 a1 = *(const bf16x8*)(Ab + offA[0][1]);                           \
    bf16x8 a2 = *(const bf16x8*)(Ab + offA[0][2]);                           \
    bf16x8 a3 = *(const bf16x8*)(Ab + offA[0][3]);                           \
    bf16x8 b0 = *(const bf16x8*)(Bb + offB[0]);                              \
    bf16x8 b1 = *(const bf16x8*)(Bb + offB[1]);                              \
    bf16x8 b2 = *(const bf16x8*)(Bb + offB[2]);                              \
    bf16x8 b3 = *(const bf16x8*)(Bb + offB[3]);                              \
    if (DOST) QSTAGE((kt) + 3);                                              \
    __builtin_amdgcn_s_setprio(1);                                           \
    acc[0][0]=mfma16(a0,b0,acc[0][0]); acc[0][1]=mfma16(a0,b1,acc[0][1]);    \
    acc[0][2]=mfma16(a0,b2,acc[0][2]); acc[0][3]=mfma16(a0,b3,acc[0][3]);    \
    acc[1][0]=mfma16(a1,b0,acc[1][0]); acc[1][1]=mfma16(a1,b1,acc[1][1]);    \
    acc[1][2]=mfma16(a1,b2,acc[1][2]); acc[1][3]=mfma16(a1,b3,acc[1][3]);    \
    acc[2][0]=mfma16(a2,b0,acc[2][0]); acc[2][1]=mfma16(a2,b1,acc[2][1]);    \
    acc[2][2]=mfma16(a2,b2,acc[2][2]); acc[2][3]=mfma16(a2,b3,acc[2][3]);    \
    acc[3][0]=mfma16(a3,b0,acc[3][0]); acc[3][1]=mfma16(a3,b1,acc[3][1]);    \
    acc[3][2]=mfma16(a3,b2,acc[3][2]); acc[3][3]=mfma16(a3,b3,acc[3][3]);    \
    __builtin_amdgcn_s_setprio(0);                                           \
    a0 = *(const bf16x8*)(Ab + offA[1][0]);                                  \
    a1 = *(const bf16x8*)(Ab + offA[1][1]);                                  \
    a2 = *(const bf16x8*)(Ab + offA[1][2]);                                  \
    a3 = *(const bf16x8*)(Ab + offA[1][3]);                                  \
    __builtin_amdgcn_s_setprio(1);                                           \
    acc[4][0]=mfma16(a0,b0,acc[4][0]); acc[4][1]=mfma16(a0,b1,acc[4][1]);    \
    acc[4][2]=mfma16(a0,b2,acc[4][2]); acc[4][3]=mfma16(a0,b3,acc[4][3]);    \
    acc[5][0]=mfma16(a1,b0,acc[5][0]); acc[5][1]=mfma16(a1,b1,acc[5][1]);    \
    acc[5][2]=mfma16(a1,b2,acc[5][2]); acc[5][3]=mfma16(a1,b3,acc[5][3]);    \
    acc[6][0]=mfma16(a2,b0,acc[6][0]); acc[6][1]=mfma16(a2,b1,acc[6][1]);    \
    acc[6][2]=mfma16(a2,b2,acc[6][2]); acc[6][3]=mfma16(a2,b3,acc[6][3]);    \
    acc[7][0]=mfma16(a3,b0,acc[7][0]); acc[7][1]=mfma16(a3,b1,acc[7][1]);    \
    acc[7][2]=mfma16(a3,b2,acc[7][2]); acc[7][3]=mfma16(a3,b3,acc[7][3]);    \
    __builtin_amdgcn_s_setprio(0); }

  // prologue: 3 K-tiles in flight
  QSTAGE(0); QSTAGE(1); QSTAGE(2);

#pragma unroll 1
  for (int kt = 0; kt < 29; ++kt) {
    QKTILE(kt, "8", 1);
  }
  QKTILE(29, "8", 0);
  QKTILE(30, "4", 0);
  QKTILE(31, "0", 0);
#undef QSTAGE
#undef QKTILE

  // ------------------------- epilogue ---------------------------------
  const int ft = m0 >> 8;                            // feature-tile 0..11
  if (ft < 8) {
    // Q/K: flash-verified relayout -> coalesced frag16x64 stores.
#pragma unroll
    for (int g = 0; g < 2; g++) {                    // 64-feature group
      const int fb = m0 + wr * 128 + g * 64;
      const bool isQ = (fb < Dc);
      unsigned short* const dstm = isQ ? Qf : Kf;
      const int head = (isQ ? fb : fb - Dc) >> 6;
      float4 b4[4];
#pragma unroll
      for (int mq = 0; mq < 4; mq++)
        b4[mq] = *(const float4*)(bias + fb + mq * 16 + lg * 4);
#pragma unroll
      for (int n = 0; n < 4; n++) {
        unsigned w8[4][2];
#pragma unroll
        for (int mq = 0; mq < 4; mq++) {
          float e0 = acc[g * 4 + mq][n][0] + b4[mq].x;
          float e1 = acc[g * 4 + mq][n][1] + b4[mq].y;
          float e2 = acc[g * 4 + mq][n][2] + b4[mq].z;
          float e3 = acc[g * 4 + mq][n][3] + b4[mq].w;
          if (isQ) {
            e0 *= 0.18033688f; e1 *= 0.18033688f;    // (1/8)*log2(e)
            e2 *= 0.18033688f; e3 *= 0.18033688f;
          }
          asm("v_cvt_pk_bf16_f32 %0, %1, %2" : "=v"(w8[mq][0]) : "v"(e0), "v"(e1));
          asm("v_cvt_pk_bf16_f32 %0, %1, %2" : "=v"(w8[mq][1]) : "v"(e2), "v"(e3));
        }
        const int t = n0 + wc * 64 + n * 16;         // token base (lr within)
        const int bb = t >> 11, tl = t & 2047;
        unsigned short* dst = dstm + (size_t)(bb * 16 + head) * 131072
                            + (tl >> 4) * 1024;
#pragma unroll
        for (int half = 0; half < 2; half++) {
          unsigned a0 = w8[2 * half][0], c0 = w8[2 * half + 1][0];
          unsigned a1 = w8[2 * half][1], c1 = w8[2 * half + 1][1];
          pl32swap(a0, c0);
          pl32swap(a1, c1);
          pl16swap(a0, c0);
          pl16swap(a1, c1);
          u32x4 w = { a0, a1, c0, c1 };
          *(u32x4*)(dst + half * 512 + lane * 8) = w;
        }
      }
    }
  } else {
    // V: scatter into V^T frag16x64 (verified path)
#pragma unroll
    for (int m = 0; m < 8; m++)
#pragma unroll
      for (int n = 0; n < 4; n++)
#pragma unroll
        for (int r = 0; r < 4; r++) {
          int f = m0 + wr * 128 + m * 16 + lg * 4 + r;
          int t = n0 + wc * 64 + n * 16 + lr;
          float v = acc[m][n][r] + bias[f];
          int c = f - 2 * Dc, head = c >> 6, d = c & 63;
          int bb = t >> 11, tl = t & 2047;
          Vf[(size_t)(bb * 16 + head) * 131072 + (tl >> 6) * 4096
             + fragaddr(d, tl & 63)] = f2bf(v);
        }
  }
}

// ---------------------------------------------------------------------------
// gemm_bt (verified 128x128 structure) -- output projection, fp32 out.
// ---------------------------------------------------------------------------
__global__ __launch_bounds__(256) void gemm_bt(const unsigned short* __restrict__ A,
                                               const unsigned short* __restrict__ Bt,
                                               const float* __restrict__ bias,
                                               float* __restrict__ Cout,
                                               int N, int K) {
  __shared__ unsigned short As[128 * 64];
  __shared__ unsigned short Bs[128 * 64];
  const int tid = threadIdx.x;
  const int lane = tid & 63, wid = tid >> 6;
  const int lr = lane & 15, lg = lane >> 4;
  const int wrow = wid >> 1, wcol = wid & 1;
  const int m0 = blockIdx.y * 128, n0 = blockIdx.x * 128;

  f32x4 acc[4][4] = {};

  for (int k0 = 0; k0 < K; k0 += 64) {
#pragma unroll
    for (int i = 0; i < 4; i++) {
      int ci = i * 256 + tid;
      int row = ci >> 3, ph = ci & 7;
      int cl = ph ^ (row & 7);
      gload_lds16(A + (size_t)(m0 + row) * K + k0 + cl * 8, As + (size_t)(i * 256 + wid * 64) * 8);
      gload_lds16(Bt + (size_t)(n0 + row) * K + k0 + cl * 8, Bs + (size_t)(i * 256 + wid * 64) * 8);
    }
    asm volatile("s_waitcnt vmcnt(0)" ::: "memory");
    __syncthreads();
#pragma unroll
    for (int kk = 0; kk < 2; kk++) {
      bf16x8 av[4], bv[4];
#pragma unroll
      for (int m = 0; m < 4; m++) {
        int row = wrow * 64 + m * 16 + lr;
        int ph = (kk * 4 + lg) ^ (row & 7);
        av[m] = *(const bf16x8*)(As + row * 64 + ph * 8);
      }
#pragma unroll
      for (int n = 0; n < 4; n++) {
        int row = wcol * 64 + n * 16 + lr;
        int ph = (kk * 4 + lg) ^ (row & 7);
        bv[n] = *(const bf16x8*)(Bs + row * 64 + ph * 8);
      }
#pragma unroll
      for (int m = 0; m < 4; m++)
#pragma unroll
        for (int n = 0; n < 4; n++)
          acc[m][n] = mfma16(av[m], bv[n], acc[m][n]);
    }
    __syncthreads();
  }

#pragma unroll
  for (int m = 0; m < 4; m++)
#pragma unroll
    for (int n = 0; n < 4; n++)
#pragma unroll
      for (int r = 0; r < 4; r++) {
        int row = m0 + wrow * 64 + m * 16 + lg * 4 + r;
        int col = n0 + wcol * 64 + n * 16 + lr;
        Cout[(size_t)row * N + col] = acc[m][n][r] + bias[col];
      }
}

// ---------------------------------------------------------------------------
// flash7 (byte-identical to verified round-9 kernel)
// ---------------------------------------------------------------------------
__global__ __launch_bounds__(256, 2) void flash7(const unsigned short* __restrict__ Qf,
                                                 const unsigned short* __restrict__ Kf,
                                                 const unsigned short* __restrict__ Vf,
                                                 const int* __restrict__ mask,
                                                 unsigned short* __restrict__ merged) {
  const int tid = threadIdx.x;
  const int lane = tid & 63, wid = tid >> 6;
  const int lr = lane & 15, lg = lane >> 4;

  // XCD-bijective swizzle: 8 q-blocks of one head land on one XCD.
  const int lin = blockIdx.y * 8 + blockIdx.x;      // 0..511
  const int swz = (lin & 7) * 64 + (lin >> 3);
  const int qb = swz & 7, bh = swz >> 3;
  const int b = bh >> 4, h = bh & 15;
  const int wq = qb * 256 + wid * 64;               // wave's q base

  const unsigned short* Qb = Qf + (size_t)bh * 131072;
  const unsigned short* Kb = Kf + (size_t)bh * 131072;
  const unsigned short* Vb = Vf + (size_t)bh * 131072;

  bf16x8 qf[4][2];
#pragma unroll
  for (int qn = 0; qn < 4; qn++)
#pragma unroll
    for (int kk = 0; kk < 2; kk++)
      qf[qn][kk] = *(const bf16x8*)(Qb + ((wq >> 4) + qn) * 1024 + kk * 512 + lane * 8);

  f32x4 o[4][4] = {};
  f32x4 lacc[4] = {};

  bf16x8 ones;
#pragma unroll
  for (int j = 0; j < 8; j++) ones[j] = (bf16_t)1.0f;

  // whole-mask all-ones check (8 coalesced int4 loads), hoisted
  bool allone = true;
#pragma unroll
  for (int j = 0; j < 8; j++) {
    int4 mv = ((const int4*)mask)[j * 64 + lane];
    allone = allone && (mv.x != 0) && (mv.y != 0) && (mv.z != 0) && (mv.w != 0);
  }
  const bool nomask = (__ballot(allone) == ~0ull);

#pragma unroll 2
  for (int tile = 0; tile < 32; tile++) {
    bf16x8 kf[4][2];
#pragma unroll
    for (int n = 0; n < 4; n++)
#pragma unroll
      for (int kk = 0; kk < 2; kk++)
        kf[n][kk] = *(const bf16x8*)(Kb + (tile * 4 + n) * 1024 + kk * 512 + lane * 8);
    bf16x8 vf[4][2];
#pragma unroll
    for (int dn = 0; dn < 4; dn++)
#pragma unroll
      for (int kk = 0; kk < 2; kk++)
        vf[dn][kk] = *(const bf16x8*)(Vb + tile * 4096 + dn * 1024 + kk * 512 + lane * 8);

    unsigned long long mb = ~0ull;
    if (!nomask) mb = __ballot(mask[tile * 64 + lane] != 0);

    unsigned pk[4][4][2];
#pragma unroll
    for (int kvn = 0; kvn < 4; kvn++) {
      f32x4 st[4] = {};
#pragma unroll
      for (int qn = 0; qn < 4; qn++) {
        st[qn] = mfma16(kf[kvn][0], qf[qn][0], st[qn]);
        st[qn] = mfma16(kf[kvn][1], qf[qn][1], st[qn]);
      }
      if (mb != ~0ull) {
#pragma unroll
        for (int r = 0; r < 4; r++)
          if (!((mb >> (kvn * 16 + lg * 4 + r)) & 1ull)) {
#pragma unroll
            for (int qn = 0; qn < 4; qn++) st[qn][r] = -1e30f;
          }
      }
#pragma unroll
      for (int qn = 0; qn < 4; qn++) {
        float e[4];
#pragma unroll
        for (int r = 0; r < 4; r++)
          asm("v_exp_f32 %0, %1" : "=v"(e[r]) : "v"(st[qn][r]));
        asm("v_cvt_pk_bf16_f32 %0, %1, %2" : "=v"(pk[qn][kvn][0]) : "v"(e[0]), "v"(e[1]));
        asm("v_cvt_pk_bf16_f32 %0, %1, %2" : "=v"(pk[qn][kvn][1]) : "v"(e[2]), "v"(e[3]));
      }
    }

    bf16x8 pa[4][2];
#pragma unroll
    for (int qn = 0; qn < 4; qn++)
#pragma unroll
      for (int m = 0; m < 2; m++) {
        unsigned a0 = pk[qn][2 * m][0], b0 = pk[qn][2 * m + 1][0];
        unsigned a1 = pk[qn][2 * m][1], b1 = pk[qn][2 * m + 1][1];
        pl32swap(a0, b0);
        pl32swap(a1, b1);
        pl16swap(a0, b0);
        pl16swap(a1, b1);
        u32x4 w = { a0, a1, b0, b1 };
        pa[qn][m] = __builtin_bit_cast(bf16x8, w);
      }

    __builtin_amdgcn_s_setprio(1);
#pragma unroll
    for (int qn = 0; qn < 4; qn++) {
#pragma unroll
      for (int dn = 0; dn < 4; dn++) {
        o[qn][dn] = mfma16(pa[qn][0], vf[dn][0], o[qn][dn]);
        o[qn][dn] = mfma16(pa[qn][1], vf[dn][1], o[qn][dn]);
      }
      lacc[qn] = mfma16(pa[qn][0], ones, lacc[qn]);
      lacc[qn] = mfma16(pa[qn][1], ones, lacc[qn]);
    }
    __builtin_amdgcn_s_setprio(0);
  }

#pragma unroll
  for (int qn = 0; qn < 4; qn++)
#pragma unroll
    for (int r = 0; r < 4; r++) {
      float inv = 1.0f / lacc[qn][r];
      int grow = b * Tc + wq + qn * 16 + lg * 4 + r;
#pragma unroll
      for (int dn = 0; dn < 4; dn++) {
        int gcol = h * HDc + dn * 16 + lr;
        merged[(size_t)grow * Dc + gcol] = f2bf(o[qn][dn][r] * inv);
      }
    }
}

// ---------------------------------------------------------------------------
extern "C" void kernel_launch(void* const* d_in, const int* in_sizes, int n_in,
                              void* d_out, int out_size, void* d_ws, size_t ws_size,
                              hipStream_t stream) {
  const float* embed = (const float*)d_in[0];
  const int*   mask  = (const int*)d_in[1];
  const float* Wq = (const float*)d_in[2];
  const float* bq = (const float*)d_in[3];
  const float* Wk = (const float*)d_in[4];
  const float* bk = (const float*)d_in[5];
  const float* Wv = (const float*)d_in[6];
  const float* bv = (const float*)d_in[7];
  const float* Wo = (const float*)d_in[8];
  const float* bo = (const float*)d_in[9];
  float* out = (float*)d_out;

  char* ws = (char*)d_ws;
  unsigned short* embed_bf = (unsigned short*)ws; ws += (size_t)Mc * Dc * 2;        // 16.8 MB
  unsigned short* WtAll    = (unsigned short*)ws; ws += (size_t)4 * Dc * Dc * 2;    //  8.4 MB
  float*          ball     = (float*)ws;          ws += 16384;
  unsigned short* Qf       = (unsigned short*)ws; ws += (size_t)Mc * Dc * 2;        // 16.8 MB
  unsigned short* Kf       = (unsigned short*)ws; ws += (size_t)Mc * Dc * 2;        // 16.8 MB
  unsigned short* Vf       = (unsigned short*)ws; ws += (size_t)Mc * Dc * 2;        // 16.8 MB
  unsigned short* merged   = (unsigned short*)ws; ws += (size_t)Mc * Dc * 2;        // 16.8 MB

  prep<<<8192 + 1024 + 1, 256, 0, stream>>>(embed, Wq, Wk, Wv, Wo, bq, bk, bv,
                                            embed_bf, WtAll, ball);
  gemm_qkv11<<<dim3(12, 32), 512, 0, stream>>>(WtAll, embed_bf, ball, Qf, Kf, Vf);
  flash7<<<dim3(8, 64), 256, 0, stream>>>(Qf, Kf, Vf, mask, merged);
  gemm_bt<<<dim3(8, 64), 256, 0, stream>>>(merged, WtAll + (size_t)3 * Dc * Dc, bo, out, Dc, Dc);
}

// Round 14
// 177.447 us; speedup vs baseline: 1.1176x; 1.0007x over previous
//
#include <hip/hip_runtime.h>

// ---------------------------------------------------------------------------
// SelfAttention (B=4,T=2048,D=1024,H=16,hd=64) fp32 in/out, bf16 MFMA compute.
// Pipeline (4 kernels): prep -> gemm_qkv11 (operand-swapped, permlane
// epilogue) -> flash8 (64q/wave, 8-wave blocks, 256-VGPR budget) -> out gemm.
//
// frag16x64 layout: matrix [R][64] stored per 16-row block:
//   addr(row,col) = (row>>4)*1024 + (col>>5)*512 + ((col>>3)&3)*128
//                 + (row&15)*8 + (col&7)
// ---------------------------------------------------------------------------

typedef __bf16 bf16_t;
typedef bf16_t bf16x8 __attribute__((ext_vector_type(8)));
typedef float  f32x4  __attribute__((ext_vector_type(4)));
typedef unsigned u32x4 __attribute__((ext_vector_type(4)));
typedef unsigned short u16x8 __attribute__((ext_vector_type(8)));
typedef unsigned short u16x4 __attribute__((ext_vector_type(4)));

#define DEV static __device__ __forceinline__

constexpr int Bc = 4, Tc = 2048, Dc = 1024, Hc = 16, HDc = 64;
constexpr int Mc = Bc * Tc;        // 8192 rows
constexpr int NQKV = 3 * Dc;       // 3072

DEV unsigned short f2bf(float f) {
  union { float f; unsigned u; } v; v.f = f;
  return (unsigned short)((v.u + 0x7fffu + ((v.u >> 16) & 1u)) >> 16);
}

DEV void gload_lds16(const void* g, const void* ldsbase) {
  unsigned m0v = __builtin_amdgcn_readfirstlane((unsigned)(unsigned long long)ldsbase);
  asm volatile("s_mov_b32 m0, %0\n\t"
               "global_load_lds_dwordx4 %1, off"
               :: "s"(m0v), "v"(g) : "memory");
}

DEV f32x4 mfma16(bf16x8 a, bf16x8 b, f32x4 c) {
  return __builtin_amdgcn_mfma_f32_16x16x32_bf16(a, b, c, 0, 0, 0);
}

DEV void pl32swap(unsigned& a, unsigned& b) {
  asm("v_permlane32_swap_b32 %0, %1" : "+v"(a), "+v"(b));
}
DEV void pl16swap(unsigned& a, unsigned& b) {
  asm("v_permlane16_swap_b32 %0, %1" : "+v"(a), "+v"(b));
}

// frag16x64 element address (row within a [R][64] matrix)
DEV int fragaddr(int row, int col) {
  return (row >> 4) * 1024 + ((col >> 5) << 9) + (((col >> 3) & 3) << 7)
       + ((row & 15) << 3) + (col & 7);
}

// ---------------------------------------------------------------------------
// prep: fused cvt_embed (blocks 0..8191) + wt_cvt (8192..9215) + bias (9216)
// ---------------------------------------------------------------------------
__global__ __launch_bounds__(256) void prep(const float* __restrict__ embed,
                                            const float* __restrict__ Wq,
                                            const float* __restrict__ Wk,
                                            const float* __restrict__ Wv,
                                            const float* __restrict__ Wo,
                                            const float* __restrict__ bq,
                                            const float* __restrict__ bk,
                                            const float* __restrict__ bv,
                                            unsigned short* __restrict__ embed_bf,
                                            unsigned short* __restrict__ WtAll,
                                            float* __restrict__ ball) {
  __shared__ unsigned short tile[64 * 80];
  const int bb = blockIdx.x;
  const int tid = threadIdx.x;

  if (bb < 8192) {                                   // ---- embed f32 -> bf16
    int i = bb * 256 + tid;
    float4 v = ((const float4*)embed)[i];
    u16x4 o = { f2bf(v.x), f2bf(v.y), f2bf(v.z), f2bf(v.w) };
    *(u16x4*)(embed_bf + (size_t)i * 4) = o;
    return;
  }
  if (bb < 8192 + 1024) {                            // ---- W -> W^T bf16
    int wb = bb - 8192;
    int bx = wb & 15, by = (wb >> 4) & 15, bz = wb >> 8;
    const float* W = bz == 0 ? Wq : bz == 1 ? Wk : bz == 2 ? Wv : Wo;
    unsigned short* dst = WtAll + (size_t)bz * 1024 * 1024;
    const int kb = by * 64, nb = bx * 64;
#pragma unroll
    for (int i = 0; i < 4; i++) {
      int ci = i * 256 + tid;
      int r = ci >> 4, c4 = ci & 15;
      float4 v = *(const float4*)(W + (size_t)(kb + r) * 1024 + nb + c4 * 4);
      u16x4 o = { f2bf(v.x), f2bf(v.y), f2bf(v.z), f2bf(v.w) };
      *(u16x4*)(tile + r * 80 + c4 * 4) = o;
    }
    __syncthreads();
#pragma unroll
    for (int i = 0; i < 2; i++) {
      int ci = i * 256 + tid;
      int n = ci >> 3, c8 = ci & 7;
      u16x8 o;
#pragma unroll
      for (int j = 0; j < 8; j++) o[j] = tile[(c8 * 8 + j) * 80 + n];
      *(u16x8*)(dst + (size_t)(nb + n) * 1024 + kb + c8 * 8) = o;
    }
    return;
  }
  // ---- bias concat (single block)
#pragma unroll
  for (int it = 0; it < 12; it++) {
    int i = it * 256 + tid;
    ball[i] = (i < 1024) ? bq[i] : (i < 2048) ? bk[i - 1024] : bv[i - 2048];
  }
}

// ---------------------------------------------------------------------------
// gemm_qkv11 (verified round-13): operand-swapped QKV projection.
// C'[f][t] = Wt[f][:] . embed[t][:]. 256(f) x 256(t), BK=32, counted-vmcnt.
// Q/K epilogue: in-register relayout (cvt_pk + permlane) -> coalesced
// frag16x64 stores. V: scatter into V^T frag16x64.
// ---------------------------------------------------------------------------
__global__ __launch_bounds__(512, 2) void gemm_qkv11(
    const unsigned short* __restrict__ Wt,     // WtAll    [3072][1024]
    const unsigned short* __restrict__ Eb,     // embed_bf [8192][1024]
    const float* __restrict__ bias,            // ball[3072]
    unsigned short* __restrict__ Qf,
    unsigned short* __restrict__ Kf,
    unsigned short* __restrict__ Vf) {
  __shared__ unsigned short As_[4 * 8192];     // 64 KB (Wt rows)
  __shared__ unsigned short Bs_[4 * 8192];     // 64 KB (embed rows)

  const int tid = threadIdx.x;
  const int lane = tid & 63, wid = tid >> 6;
  const int lr = lane & 15, lg = lane >> 4;
  const int wr = wid >> 2, wc = wid & 3;

  const int lin = blockIdx.y * 12 + blockIdx.x;        // 0..383
  const int swz = (lin & 7) * 48 + (lin >> 3);
  const int m0 = (swz % 12) * 256, n0 = (swz / 12) * 256;

  size_t gA[2], gB[2];
  int ldsoff[2];
#pragma unroll
  for (int i = 0; i < 2; i++) {
    int ci = i * 512 + tid;
    int row = ci >> 2;
    int cl = (ci & 3) ^ ((row ^ (row >> 2)) & 3);
    gA[i] = (size_t)(m0 + row) * 1024 + cl * 8;
    gB[i] = (size_t)(n0 + row) * 1024 + cl * 8;
    ldsoff[i] = ci * 8;
  }

  int offA[2][4], offB[4];
#pragma unroll
  for (int mq = 0; mq < 2; mq++)
#pragma unroll
    for (int m = 0; m < 4; m++) {
      int row = wr * 128 + mq * 64 + m * 16 + lr;
      offA[mq][m] = row * 32 + ((lg ^ ((row ^ (row >> 2)) & 3)) << 3);
    }
#pragma unroll
  for (int n = 0; n < 4; n++) {
    int row = wc * 64 + n * 16 + lr;
    offB[n] = row * 32 + ((lg ^ ((row ^ (row >> 2)) & 3)) << 3);
  }

  f32x4 acc[8][4] = {};

#define QSTAGE(kt) {                                                         \
    const int sbi_ = (kt) & 3;                                               \
    _Pragma("unroll")                                                        \
    for (int i_ = 0; i_ < 2; i_++) {                                         \
      gload_lds16(Wt + gA[i_] + (size_t)(kt) * 32,                           \
                  As_ + sbi_ * 8192 + ldsoff[i_]);                           \
      gload_lds16(Eb + gB[i_] + (size_t)(kt) * 32,                           \
                  Bs_ + sbi_ * 8192 + ldsoff[i_]);                           \
    } }

#define QKTILE(kt, VM, DOST) {                                               \
    const int bi_ = (kt) & 3;                                                \
    const unsigned short* Ab = As_ + bi_ * 8192;                             \
    const unsigned short* Bb = Bs_ + bi_ * 8192;                             \
    asm volatile("s_waitcnt vmcnt(" VM ")" ::: "memory");                    \
    asm volatile("s_barrier" ::: "memory");                                  \
    bf16x8 a0 = *(const bf16x8*)(Ab + offA[0][0]);                           \
    bf16x8 a1 = *(const bf16x8*)(Ab + offA[0][1]);                           \
    bf16x8 a2 = *(const bf16x8*)(Ab + offA[0][2]);                           \
    bf16x8 a3 = *(const bf16x8*)(Ab + offA[0][3]);                           \
    bf16x8 b0 = *(const bf16x8*)(Bb + offB[0]);                              \
    bf16x8 b1 = *(const bf16x8*)(Bb + offB[1]);                              \
    bf16x8 b2 = *(const bf16x8*)(Bb + offB[2]);                              \
    bf16x8 b3 = *(const bf16x8*)(Bb + offB[3]);                              \
    if (DOST) QSTAGE((kt) + 3);                                              \
    __builtin_amdgcn_s_setprio(1);                                           \
    acc[0][0]=mfma16(a0,b0,acc[0][0]); acc[0][1]=mfma16(a0,b1,acc[0][1]);    \
    acc[0][2]=mfma16(a0,b2,acc[0][2]); acc[0][3]=mfma16(a0,b3,acc[0][3]);    \
    acc[1][0]=mfma16(a1,b0,acc[1][0]); acc[1][1]=mfma16(a1,b1,acc[1][1]);    \
    acc[1][2]=mfma16(a1,b2,acc[1][2]); acc[1][3]=mfma16(a1,b3,acc[1][3]);    \
    acc[2][0]=mfma16(a2,b0,acc[2][0]); acc[2][1]=mfma16(a2,b1,acc[2][1]);    \
    acc[2][2]=mfma16(a2,b2,acc[2][2]); acc[2][3]=mfma16(a2,b3,acc[2][3]);    \
    acc[3][0]=mfma16(a3,b0,acc[3][0]); acc[3][1]=mfma16(a3,b1,acc[3][1]);    \
    acc[3][2]=mfma16(a3,b2,acc[3][2]); acc[3][3]=mfma16(a3,b3,acc[3][3]);    \
    __builtin_amdgcn_s_setprio(0);                                           \
    a0 = *(const bf16x8*)(Ab + offA[1][0]);                                  \
    a1 = *(const bf16x8*)(Ab + offA[1][1]);                                  \
    a2 = *(const bf16x8*)(Ab + offA[1][2]);                                  \
    a3 = *(const bf16x8*)(Ab + offA[1][3]);                                  \
    __builtin_amdgcn_s_setprio(1);                                           \
    acc[4][0]=mfma16(a0,b0,acc[4][0]); acc[4][1]=mfma16(a0,b1,acc[4][1]);    \
    acc[4][2]=mfma16(a0,b2,acc[4][2]); acc[4][3]=mfma16(a0,b3,acc[4][3]);    \
    acc[5][0]=mfma16(a1,b0,acc[5][0]); acc[5][1]=mfma16(a1,b1,acc[5][1]);    \
    acc[5][2]=mfma16(a1,b2,acc[5][2]); acc[5][3]=mfma16(a1,b3,acc[5][3]);    \
    acc[6][0]=mfma16(a2,b0,acc[6][0]); acc[6][1]=mfma16(a2,b1,acc[6][1]);    \
    acc[6][2]=mfma16(a2,b2,acc[6][2]); acc[6][3]=mfma16(a2,b3,acc[6][3]);    \
    acc[7][0]=mfma16(a3,b0,acc[7][0]); acc[7][1]=mfma16(a3,b1,acc[7][1]);    \
    acc[7][2]=mfma16(a3,b2,acc[7][2]); acc[7][3]=mfma16(a3,b3,acc[7][3]);    \
    __builtin_amdgcn_s_setprio(0); }

  // prologue: 3 K-tiles in flight
  QSTAGE(0); QSTAGE(1); QSTAGE(2);

#pragma unroll 1
  for (int kt = 0; kt < 29; ++kt) {
    QKTILE(kt, "8", 1);
  }
  QKTILE(29, "8", 0);
  QKTILE(30, "4", 0);
  QKTILE(31, "0", 0);
#undef QSTAGE
#undef QKTILE

  // ------------------------- epilogue ---------------------------------
  const int ft = m0 >> 8;                            // feature-tile 0..11
  if (ft < 8) {
    // Q/K: flash-verified relayout -> coalesced frag16x64 stores.
#pragma unroll
    for (int g = 0; g < 2; g++) {                    // 64-feature group
      const int fb = m0 + wr * 128 + g * 64;
      const bool isQ = (fb < Dc);
      unsigned short* const dstm = isQ ? Qf : Kf;
      const int head = (isQ ? fb : fb - Dc) >> 6;
      float4 b4[4];
#pragma unroll
      for (int mq = 0; mq < 4; mq++)
        b4[mq] = *(const float4*)(bias + fb + mq * 16 + lg * 4);
#pragma unroll
      for (int n = 0; n < 4; n++) {
        unsigned w8[4][2];
#pragma unroll
        for (int mq = 0; mq < 4; mq++) {
          float e0 = acc[g * 4 + mq][n][0] + b4[mq].x;
          float e1 = acc[g * 4 + mq][n][1] + b4[mq].y;
          float e2 = acc[g * 4 + mq][n][2] + b4[mq].z;
          float e3 = acc[g * 4 + mq][n][3] + b4[mq].w;
          if (isQ) {
            e0 *= 0.18033688f; e1 *= 0.18033688f;    // (1/8)*log2(e)
            e2 *= 0.18033688f; e3 *= 0.18033688f;
          }
          asm("v_cvt_pk_bf16_f32 %0, %1, %2" : "=v"(w8[mq][0]) : "v"(e0), "v"(e1));
          asm("v_cvt_pk_bf16_f32 %0, %1, %2" : "=v"(w8[mq][1]) : "v"(e2), "v"(e3));
        }
        const int t = n0 + wc * 64 + n * 16;         // token base (lr within)
        const int bb = t >> 11, tl = t & 2047;
        unsigned short* dst = dstm + (size_t)(bb * 16 + head) * 131072
                            + (tl >> 4) * 1024;
#pragma unroll
        for (int half = 0; half < 2; half++) {
          unsigned a0 = w8[2 * half][0], c0 = w8[2 * half + 1][0];
          unsigned a1 = w8[2 * half][1], c1 = w8[2 * half + 1][1];
          pl32swap(a0, c0);
          pl32swap(a1, c1);
          pl16swap(a0, c0);
          pl16swap(a1, c1);
          u32x4 w = { a0, a1, c0, c1 };
          *(u32x4*)(dst + half * 512 + lane * 8) = w;
        }
      }
    }
  } else {
    // V: scatter into V^T frag16x64 (verified path)
#pragma unroll
    for (int m = 0; m < 8; m++)
#pragma unroll
      for (int n = 0; n < 4; n++)
#pragma unroll
        for (int r = 0; r < 4; r++) {
          int f = m0 + wr * 128 + m * 16 + lg * 4 + r;
          int t = n0 + wc * 64 + n * 16 + lr;
          float v = acc[m][n][r] + bias[f];
          int c = f - 2 * Dc, head = c >> 6, d = c & 63;
          int bb = t >> 11, tl = t & 2047;
          Vf[(size_t)(bb * 16 + head) * 131072 + (tl >> 6) * 4096
             + fragaddr(d, tl & 63)] = f2bf(v);
        }
  }
}

// ---------------------------------------------------------------------------
// gemm_bt (verified 128x128 structure) -- output projection, fp32 out.
// ---------------------------------------------------------------------------
__global__ __launch_bounds__(256) void gemm_bt(const unsigned short* __restrict__ A,
                                               const unsigned short* __restrict__ Bt,
                                               const float* __restrict__ bias,
                                               float* __restrict__ Cout,
                                               int N, int K) {
  __shared__ unsigned short As[128 * 64];
  __shared__ unsigned short Bs[128 * 64];
  const int tid = threadIdx.x;
  const int lane = tid & 63, wid = tid >> 6;
  const int lr = lane & 15, lg = lane >> 4;
  const int wrow = wid >> 1, wcol = wid & 1;
  const int m0 = blockIdx.y * 128, n0 = blockIdx.x * 128;

  f32x4 acc[4][4] = {};

  for (int k0 = 0; k0 < K; k0 += 64) {
#pragma unroll
    for (int i = 0; i < 4; i++) {
      int ci = i * 256 + tid;
      int row = ci >> 3, ph = ci & 7;
      int cl = ph ^ (row & 7);
      gload_lds16(A + (size_t)(m0 + row) * K + k0 + cl * 8, As + (size_t)(i * 256 + wid * 64) * 8);
      gload_lds16(Bt + (size_t)(n0 + row) * K + k0 + cl * 8, Bs + (size_t)(i * 256 + wid * 64) * 8);
    }
    asm volatile("s_waitcnt vmcnt(0)" ::: "memory");
    __syncthreads();
#pragma unroll
    for (int kk = 0; kk < 2; kk++) {
      bf16x8 av[4], bv[4];
#pragma unroll
      for (int m = 0; m < 4; m++) {
        int row = wrow * 64 + m * 16 + lr;
        int ph = (kk * 4 + lg) ^ (row & 7);
        av[m] = *(const bf16x8*)(As + row * 64 + ph * 8);
      }
#pragma unroll
      for (int n = 0; n < 4; n++) {
        int row = wcol * 64 + n * 16 + lr;
        int ph = (kk * 4 + lg) ^ (row & 7);
        bv[n] = *(const bf16x8*)(Bs + row * 64 + ph * 8);
      }
#pragma unroll
      for (int m = 0; m < 4; m++)
#pragma unroll
        for (int n = 0; n < 4; n++)
          acc[m][n] = mfma16(av[m], bv[n], acc[m][n]);
    }
    __syncthreads();
  }

#pragma unroll
  for (int m = 0; m < 4; m++)
#pragma unroll
    for (int n = 0; n < 4; n++)
#pragma unroll
      for (int r = 0; r < 4; r++) {
        int row = m0 + wrow * 64 + m * 16 + lg * 4 + r;
        int col = n0 + wcol * 64 + n * 16 + lr;
        Cout[(size_t)row * N + col] = acc[m][n][r] + bias[col];
      }
}

// ---------------------------------------------------------------------------
// flash8: flash7 body verbatim, repackaged as 8-wave (512-thread) blocks so
// launch_bounds(512) permits up to 256 VGPR/wave (2 waves/SIMD mandatory for
// an 8-wave block) -- restores cross-tile K/V register prefetch that the
// 128-VGPR cap of (256,2) was blocking. Grid (4 qb, 64 bh) = 256 blocks =
// 1/CU, one round. XCD swizzle: xcd = lin&7, 32 blocks/XCD = 8 heads x 4 qb.
// ---------------------------------------------------------------------------
__global__ __launch_bounds__(512) void flash8(const unsigned short* __restrict__ Qf,
                                              const unsigned short* __restrict__ Kf,
                                              const unsigned short* __restrict__ Vf,
                                              const int* __restrict__ mask,
                                              unsigned short* __restrict__ merged) {
  const int tid = threadIdx.x;
  const int lane = tid & 63, wid = tid >> 6;   // wid 0..7
  const int lr = lane & 15, lg = lane >> 4;

  const int lin = blockIdx.y * 4 + blockIdx.x;      // 0..255
  const int swz = (lin & 7) * 32 + (lin >> 3);
  const int qb = swz & 3, bh = swz >> 2;
  const int b = bh >> 4, h = bh & 15;
  const int wq = qb * 512 + wid * 64;               // wave's q base

  const unsigned short* Qb = Qf + (size_t)bh * 131072;
  const unsigned short* Kb = Kf + (size_t)bh * 131072;
  const unsigned short* Vb = Vf + (size_t)bh * 131072;

  bf16x8 qf[4][2];
#pragma unroll
  for (int qn = 0; qn < 4; qn++)
#pragma unroll
    for (int kk = 0; kk < 2; kk++)
      qf[qn][kk] = *(const bf16x8*)(Qb + ((wq >> 4) + qn) * 1024 + kk * 512 + lane * 8);

  f32x4 o[4][4] = {};
  f32x4 lacc[4] = {};

  bf16x8 ones;
#pragma unroll
  for (int j = 0; j < 8; j++) ones[j] = (bf16_t)1.0f;

  // whole-mask all-ones check (8 coalesced int4 loads), hoisted
  bool allone = true;
#pragma unroll
  for (int j = 0; j < 8; j++) {
    int4 mv = ((const int4*)mask)[j * 64 + lane];
    allone = allone && (mv.x != 0) && (mv.y != 0) && (mv.z != 0) && (mv.w != 0);
  }
  const bool nomask = (__ballot(allone) == ~0ull);

#pragma unroll 2
  for (int tile = 0; tile < 32; tile++) {
    bf16x8 kf[4][2];
#pragma unroll
    for (int n = 0; n < 4; n++)
#pragma unroll
      for (int kk = 0; kk < 2; kk++)
        kf[n][kk] = *(const bf16x8*)(Kb + (tile * 4 + n) * 1024 + kk * 512 + lane * 8);
    bf16x8 vf[4][2];
#pragma unroll
    for (int dn = 0; dn < 4; dn++)
#pragma unroll
      for (int kk = 0; kk < 2; kk++)
        vf[dn][kk] = *(const bf16x8*)(Vb + tile * 4096 + dn * 1024 + kk * 512 + lane * 8);

    unsigned long long mb = ~0ull;
    if (!nomask) mb = __ballot(mask[tile * 64 + lane] != 0);

    unsigned pk[4][4][2];
#pragma unroll
    for (int kvn = 0; kvn < 4; kvn++) {
      f32x4 st[4] = {};
#pragma unroll
      for (int qn = 0; qn < 4; qn++) {
        st[qn] = mfma16(kf[kvn][0], qf[qn][0], st[qn]);
        st[qn] = mfma16(kf[kvn][1], qf[qn][1], st[qn]);
      }
      if (mb != ~0ull) {
#pragma unroll
        for (int r = 0; r < 4; r++)
          if (!((mb >> (kvn * 16 + lg * 4 + r)) & 1ull)) {
#pragma unroll
            for (int qn = 0; qn < 4; qn++) st[qn][r] = -1e30f;
          }
      }
#pragma unroll
      for (int qn = 0; qn < 4; qn++) {
        float e[4];
#pragma unroll
        for (int r = 0; r < 4; r++)
          asm("v_exp_f32 %0, %1" : "=v"(e[r]) : "v"(st[qn][r]));
        asm("v_cvt_pk_bf16_f32 %0, %1, %2" : "=v"(pk[qn][kvn][0]) : "v"(e[0]), "v"(e[1]));
        asm("v_cvt_pk_bf16_f32 %0, %1, %2" : "=v"(pk[qn][kvn][1]) : "v"(e[2]), "v"(e[3]));
      }
    }

    bf16x8 pa[4][2];
#pragma unroll
    for (int qn = 0; qn < 4; qn++)
#pragma unroll
      for (int m = 0; m < 2; m++) {
        unsigned a0 = pk[qn][2 * m][0], b0 = pk[qn][2 * m + 1][0];
        unsigned a1 = pk[qn][2 * m][1], b1 = pk[qn][2 * m + 1][1];
        pl32swap(a0, b0);
        pl32swap(a1, b1);
        pl16swap(a0, b0);
        pl16swap(a1, b1);
        u32x4 w = { a0, a1, b0, b1 };
        pa[qn][m] = __builtin_bit_cast(bf16x8, w);
      }

    __builtin_amdgcn_s_setprio(1);
#pragma unroll
    for (int qn = 0; qn < 4; qn++) {
#pragma unroll
      for (int dn = 0; dn < 4; dn++) {
        o[qn][dn] = mfma16(pa[qn][0], vf[dn][0], o[qn][dn]);
        o[qn][dn] = mfma16(pa[qn][1], vf[dn][1], o[qn][dn]);
      }
      lacc[qn] = mfma16(pa[qn][0], ones, lacc[qn]);
      lacc[qn] = mfma16(pa[qn][1], ones, lacc[qn]);
    }
    __builtin_amdgcn_s_setprio(0);
  }

#pragma unroll
  for (int qn = 0; qn < 4; qn++)
#pragma unroll
    for (int r = 0; r < 4; r++) {
      float inv = 1.0f / lacc[qn][r];
      int grow = b * Tc + wq + qn * 16 + lg * 4 + r;
#pragma unroll
      for (int dn = 0; dn < 4; dn++) {
        int gcol = h * HDc + dn * 16 + lr;
        merged[(size_t)grow * Dc + gcol] = f2bf(o[qn][dn][r] * inv);
      }
    }
}

// ---------------------------------------------------------------------------
extern "C" void kernel_launch(void* const* d_in, const int* in_sizes, int n_in,
                              void* d_out, int out_size, void* d_ws, size_t ws_size,
                              hipStream_t stream) {
  const float* embed = (const float*)d_in[0];
  const int*   mask  = (const int*)d_in[1];
  const float* Wq = (const float*)d_in[2];
  const float* bq = (const float*)d_in[3];
  const float* Wk = (const float*)d_in[4];
  const float* bk = (const float*)d_in[5];
  const float* Wv = (const float*)d_in[6];
  const float* bv = (const float*)d_in[7];
  const float* Wo = (const float*)d_in[8];
  const float* bo = (const float*)d_in[9];
  float* out = (float*)d_out;

  char* ws = (char*)d_ws;
  unsigned short* embed_bf = (unsigned short*)ws; ws += (size_t)Mc * Dc * 2;        // 16.8 MB
  unsigned short* WtAll    = (unsigned short*)ws; ws += (size_t)4 * Dc * Dc * 2;    //  8.4 MB
  float*          ball     = (float*)ws;          ws += 16384;
  unsigned short* Qf       = (unsigned short*)ws; ws += (size_t)Mc * Dc * 2;        // 16.8 MB
  unsigned short* Kf       = (unsigned short*)ws; ws += (size_t)Mc * Dc * 2;        // 16.8 MB
  unsigned short* Vf       = (unsigned short*)ws; ws += (size_t)Mc * Dc * 2;        // 16.8 MB
  unsigned short* merged   = (unsigned short*)ws; ws += (size_t)Mc * Dc * 2;        // 16.8 MB

  prep<<<8192 + 1024 + 1, 256, 0, stream>>>(embed, Wq, Wk, Wv, Wo, bq, bk, bv,
                                            embed_bf, WtAll, ball);
  gemm_qkv11<<<dim3(12, 32), 512, 0, stream>>>(WtAll, embed_bf, ball, Qf, Kf, Vf);
  flash8<<<dim3(4, 64), 512, 0, stream>>>(Qf, Kf, Vf, mask, merged);
  gemm_bt<<<dim3(8, 64), 256, 0, stream>>>(merged, WtAll + (size_t)3 * Dc * Dc, bo, out, Dc, Dc);
}